// Round 20
// baseline (331.576 us; speedup 1.0000x reference)
//
#include <hip/hip_runtime.h>
#include <hip/hip_bf16.h>
#include <hip/hip_fp16.h>

#define MAXPH 0.78539816339744831f
typedef unsigned short ushort_t;
typedef _Float16 half8 __attribute__((ext_vector_type(8)));
typedef float f32x4 __attribute__((ext_vector_type(4)));

__device__ __forceinline__ float wsum64(float v) {
#pragma unroll
  for (int o = 32; o > 0; o >>= 1) v += __shfl_xor(v, o);
  return v;
}
__device__ __forceinline__ float bf2f(ushort_t u) {
  return __uint_as_float(((unsigned)u) << 16);
}

// ---- kCountPrep: blocks [0,1024) = per-dst histogram + AdjU; block 1024 = prep Wg1/C0G1
__global__ __launch_bounds__(256) void kCountPrep(
    const int* __restrict__ ei, int ne, unsigned* __restrict__ cnt,
    unsigned* __restrict__ AdjU,
    const float* __restrict__ ln_g, const float* __restrict__ ln_b,
    const float* __restrict__ w1, const float* __restrict__ b1,
    float* __restrict__ Wg1, float* __restrict__ C0G1) {
  if (blockIdx.x < 1024) {
    int t = blockIdx.x * 256 + threadIdx.x;
    int st = 1024 * 256;
    for (int e = t; e < ne; e += st) {
      int s = ei[e];
      int d = ei[ne + e];
      atomicAdd(&cnt[d], 1u);
      if ((unsigned)(s | d) < 64u) atomicAdd(&AdjU[d * 64 + s], 1u);
    }
  } else {
    int tt = threadIdx.x;
    for (int idx = tt; idx < 4096; idx += 256) {
      int j = idx >> 5;
      Wg1[idx] = ln_g[j] * w1[idx];
    }
    if (tt < 32) {
      float c0 = b1[tt], g1 = 0.f;
      for (int j = 0; j < 128; ++j) {
        float w = w1[j * 32 + tt];
        c0 = fmaf(ln_b[j], w, c0);
        g1 = fmaf(ln_g[j], w, g1);
      }
      C0G1[tt] = c0;
      C0G1[32 + tt] = g1;
    }
  }
}

// ---- kNodeMSG: blocks [0,nb) = MFMA node pipeline; block nb = coalesced scan; block nb+1 = GCN+MLP
__global__ __launch_bounds__(256) void kNodeMSG(
    const float* __restrict__ x, const float* __restrict__ Wr,
    const float* __restrict__ Wg1, const float* __restrict__ C0G1,
    const float* __restrict__ w2, const float* __restrict__ b2,
    ushort_t* __restrict__ R, float* __restrict__ AdP,
    __half* __restrict__ Crh, __half* __restrict__ Srh, int n, int ntiles, int nb,
    const unsigned* __restrict__ cnt, unsigned* __restrict__ off,
    const unsigned* __restrict__ AdjU,
    const float* __restrict__ g1w, const float* __restrict__ g1b,
    const float* __restrict__ g2w, const float* __restrict__ g2b,
    const float* __restrict__ aw1, const float* __restrict__ ab1,
    const float* __restrict__ aw2, const float* __restrict__ ab2,
    float* __restrict__ z2g) {
  __shared__ float SHF[8704];  // 34816 B union
  const int tid = threadIdx.x;
  const int bid = blockIdx.x;

  if (bid == nb) {
    // ======== coalesced 2-pass exclusive scan (4 waves × contiguous quarter) ========
    unsigned* wsums = (unsigned*)SHF;
    const int w = tid >> 6, l = tid & 63;
    const int chunk = (n + 3) >> 2;
    const int lo = w * chunk;
    const int hi = min(lo + chunk, n);
    unsigned s = 0;
    for (int i = lo + l; i < hi; i += 64) s += cnt[i];
#pragma unroll
    for (int o = 32; o > 0; o >>= 1) s += __shfl_xor(s, o);
    if (l == 0) wsums[w] = s;
    __syncthreads();
    unsigned base = 0;
    for (int i = 0; i < w; ++i) base += wsums[i];
    for (int i0 = lo; i0 < hi; i0 += 64) {
      int i = i0 + l;
      unsigned v = (i < hi) ? cnt[i] : 0u;
      unsigned inc = v;
#pragma unroll
      for (int o = 1; o < 64; o <<= 1) {
        unsigned u = __shfl_up(inc, o);
        if (l >= o) inc += u;
      }
      if (i < hi) off[i] = base + inc - v;
      base += __shfl(inc, 63);
    }
    if (w == 3 && l == 63) off[n] = base;
    return;
  }
  if (bid == nb + 1) {
    // ======== GCN x2 + pool + MLP -> z2 (256 threads, padded LDS) ========
    float* L0 = SHF;
    float* L1 = SHF + 4160;
    float* sdv = SHF + 8320;
    float* sts = sdv + 64;
    float* sgp = sts + 64;
    float* sz1 = sgp + 64;
    for (int idx = tid; idx < 4096; idx += 256) {
      int r = idx >> 6, c = idx & 63;
      L0[r * 65 + c] = (float)AdjU[idx];
    }
    __syncthreads();
    if (tid < 64) {
      float deg = 1.f;
      for (int s2 = 0; s2 < 64; ++s2) deg += L0[tid * 65 + s2];
      sdv[tid] = rsqrtf(deg);
    }
    __syncthreads();
    if (tid < 64) {
      float a = 0.f;
      for (int s2 = 0; s2 < 64; ++s2) a = fmaf(L0[tid * 65 + s2], sdv[s2], a);
      sts[tid] = a;
    }
    __syncthreads();
    for (int idx = tid; idx < 4096; idx += 256) {
      int d = idx >> 6, kk = idx & 63;
      L1[d * 65 + kk] = fmaxf(fmaf(g1w[kk], fmaf(sts[d], sdv[d], sdv[d] * sdv[d]), g1b[kk]), 0.f);
    }
    __syncthreads();
    const int i2 = tid >> 2, j0 = (tid & 3) << 4;
    float xw[16];
#pragma unroll
    for (int q = 0; q < 16; ++q) xw[q] = 0.f;
    for (int m = 0; m < 64; ++m) {
      float hm = L1[i2 * 65 + m];
      const float* wp = g2w + m * 64 + j0;
#pragma unroll
      for (int q = 0; q < 16; ++q) xw[q] = fmaf(hm, wp[q], xw[q]);
    }
    __syncthreads();
#pragma unroll
    for (int q = 0; q < 16; ++q) L1[i2 * 65 + j0 + q] = xw[q];
    __syncthreads();
    float a[16];
#pragma unroll
    for (int q = 0; q < 16; ++q) a[q] = 0.f;
    for (int s2 = 0; s2 < 64; ++s2) {
      float wv = L0[i2 * 65 + s2] * sdv[s2];
#pragma unroll
      for (int q = 0; q < 16; ++q) a[q] = fmaf(wv, L1[s2 * 65 + j0 + q], a[q]);
    }
    float di = sdv[i2], sc = di * di;
    float h2v[16];
#pragma unroll
    for (int q = 0; q < 16; ++q)
      h2v[q] = fmaf(a[q], di, fmaf(sc, L1[i2 * 65 + j0 + q], g2b[j0 + q]));
    __syncthreads();
#pragma unroll
    for (int q = 0; q < 16; ++q) L1[i2 * 65 + j0 + q] = h2v[q];
    __syncthreads();
    if (tid < 64) {
      float aa = 0.f;
      for (int d = 0; d < 64; ++d) aa += L1[d * 65 + tid];
      sgp[tid] = aa * 0.015625f;
    }
    __syncthreads();
    if (tid < 64) {
      float aa = ab1[tid];
      for (int m = 0; m < 64; ++m) aa = fmaf(sgp[m], aw1[m * 64 + tid], aa);
      sz1[tid] = fmaxf(aa, 0.f);
    }
    __syncthreads();
    if (tid < 64) {
      float aa = ab2[tid];
      for (int m = 0; m < 64; ++m) aa = fmaf(sz1[m], aw2[m * 64 + tid], aa);
      z2g[tid] = fmaxf(aa, 0.f);
    }
    return;
  }

  // ======== node MFMA path ========
  _Float16* bWr = (_Float16*)SHF;             // 4096 halves ([512][8])
  _Float16* bAd = (_Float16*)(SHF + 2048);    // 2048 halves ([256][8])
  _Float16* bAs = (_Float16*)(SHF + 3072);
  _Float16* cmT = (_Float16*)(SHF + 4096);    // 4*16*72 halves
  const int lane = tid & 63;
  const int wave = tid >> 6;
  for (int slot = tid; slot < 512; slot += 256) {
    int g = slot >> 7;
    int c = (slot >> 6) & 1;
    int l = slot & 63;
    int col = g * 16 + (l & 15);
    int kb0 = c * 32 + ((l >> 4) << 3);
#pragma unroll
    for (int j = 0; j < 8; ++j) bWr[slot * 8 + j] = (_Float16)Wr[(kb0 + j) * 64 + col];
  }
  {
    int slot = tid;
    int g2 = slot >> 7;
    int c = (slot >> 6) & 1;
    int l = slot & 63;
    int col = g2 * 16 + (l & 15);
    int kb0 = c * 32 + ((l >> 4) << 3);
#pragma unroll
    for (int j = 0; j < 8; ++j) {
      bAd[slot * 8 + j] = (_Float16)Wg1[(kb0 + j) * 32 + col];
      bAs[slot * 8 + j] = (_Float16)Wg1[(64 + kb0 + j) * 32 + col];
    }
  }
  __syncthreads();
  const int tile = bid * 4 + wave;
  if (tile >= ntiles) return;
  const int base = tile << 4;
  const int row = lane & 15;
  const int kb = (lane >> 4) << 3;
  const int nodeA = min(base + row, n - 1);
  const float* xp = x + (size_t)nodeA * 64;
  float xv[8], xh[8];
  *(float4*)&xv[0] = *(const float4*)(xp + kb);
  *(float4*)&xv[4] = *(const float4*)(xp + kb + 4);
  *(float4*)&xh[0] = *(const float4*)(xp + 32 + kb);
  *(float4*)&xh[4] = *(const float4*)(xp + 32 + kb + 4);
  float s1 = 0.f, s2 = 0.f;
#pragma unroll
  for (int j = 0; j < 8; ++j) {
    s1 += xv[j] + xh[j];
    s2 += xv[j] * xv[j] + xh[j] * xh[j];
  }
  s1 += __shfl_xor(s1, 16);
  s1 += __shfl_xor(s1, 32);
  s2 += __shfl_xor(s2, 16);
  s2 += __shfl_xor(s2, 32);
  float mean = s1 * 0.015625f;
  float var = fmaf(-mean, mean, s2 * 0.015625f);
  float rstd = rsqrtf(var + 1e-5f);
  half8 aLo, aHi;
#pragma unroll
  for (int j = 0; j < 8; ++j) {
    aLo[j] = (_Float16)((xv[j] - mean) * rstd);
    aHi[j] = (_Float16)((xh[j] - mean) * rstd);
  }
  f32x4 accH[4];
#pragma unroll
  for (int g = 0; g < 4; ++g) {
    f32x4 z4 = {0.f, 0.f, 0.f, 0.f};
    z4 = __builtin_amdgcn_mfma_f32_16x16x32_f16(aLo, *(const half8*)&bWr[(g * 128 + lane) * 8], z4, 0, 0, 0);
    z4 = __builtin_amdgcn_mfma_f32_16x16x32_f16(aHi, *(const half8*)&bWr[(g * 128 + 64 + lane) * 8], z4, 0, 0, 0);
    accH[g] = z4;
  }
  float cm[4][4];
  float p1[4] = {0.f, 0.f, 0.f, 0.f}, p2[4] = {0.f, 0.f, 0.f, 0.f};
#pragma unroll
  for (int g = 0; g < 4; ++g)
#pragma unroll
    for (int r = 0; r < 4; ++r) {
      float hv = accH[g][r];
      float m = fminf(sqrtf(fmaf(hv, hv, 1e-8f)), 10.f);
      cm[g][r] = m;
      p1[r] += m;
      p2[r] += m * m;
    }
#pragma unroll
  for (int o = 1; o <= 8; o <<= 1)
#pragma unroll
    for (int r = 0; r < 4; ++r) {
      p1[r] += __shfl_xor(p1[r], o);
      p2[r] += __shfl_xor(p2[r], o);
    }
  const int rgrp = (lane >> 4) << 2;
#pragma unroll
  for (int g = 0; g < 4; ++g)
#pragma unroll
    for (int r = 0; r < 4; ++r)
      cmT[((wave * 16) + rgrp + r) * 72 + g * 16 + (lane & 15)] = (_Float16)cm[g][r];
  half8 cLo = *(const half8*)&cmT[((wave * 16) + row) * 72 + kb];
  half8 cHi = *(const half8*)&cmT[((wave * 16) + row) * 72 + 32 + kb];
  f32x4 accAd[2], accAs[2];
#pragma unroll
  for (int g2 = 0; g2 < 2; ++g2) {
    f32x4 z4 = {0.f, 0.f, 0.f, 0.f};
    z4 = __builtin_amdgcn_mfma_f32_16x16x32_f16(cLo, *(const half8*)&bAd[(g2 * 128 + lane) * 8], z4, 0, 0, 0);
    z4 = __builtin_amdgcn_mfma_f32_16x16x32_f16(cHi, *(const half8*)&bAd[(g2 * 128 + 64 + lane) * 8], z4, 0, 0, 0);
    accAd[g2] = z4;
    f32x4 w4 = {0.f, 0.f, 0.f, 0.f};
    w4 = __builtin_amdgcn_mfma_f32_16x16x32_f16(cLo, *(const half8*)&bAs[(g2 * 128 + lane) * 8], w4, 0, 0, 0);
    w4 = __builtin_amdgcn_mfma_f32_16x16x32_f16(cHi, *(const half8*)&bAs[(g2 * 128 + 64 + lane) * 8], w4, 0, 0, 0);
    accAs[g2] = w4;
  }
  const float b2r = b2[0];
  float c0v[2], g1v[2], w2v[2];
#pragma unroll
  for (int g2 = 0; g2 < 2; ++g2) {
    int k = g2 * 16 + (lane & 15);
    c0v[g2] = C0G1[k];
    g1v[g2] = C0G1[32 + k];
    w2v[g2] = w2[k];
  }
  float zp[4];
#pragma unroll
  for (int r = 0; r < 4; ++r) {
    float meanE = p1[r] * 0.015625f;
    float varE = fmaf(-meanE, meanE, p2[r] * 0.015625f);
    float rstdE = rsqrtf(varE + 1e-5f);
    float zz = 0.f;
#pragma unroll
    for (int g2 = 0; g2 < 2; ++g2) {
      float pre = fmaf(rstdE, fmaf(-meanE, g1v[g2], accAd[g2][r] + accAs[g2][r]), c0v[g2]);
      zz = fmaf(fmaxf(pre, 0.f), w2v[g2], zz);
    }
    zp[r] = zz;
  }
#pragma unroll
  for (int o = 1; o <= 8; o <<= 1)
#pragma unroll
    for (int r = 0; r < 4; ++r) zp[r] += __shfl_xor(zp[r], o);
  float csv[4], snv[4];
#pragma unroll
  for (int r = 0; r < 4; ++r) {
    float coup = 1.f / (1.f + expf(-(zp[r] + b2r)));
    float ph = fminf(0.3f * coup, MAXPH);
    sincosf(ph, &snv[r], &csv[r]);
  }
  const int colb = lane & 15;
#pragma unroll
  for (int r = 0; r < 4; ++r) {
    int node = base + rgrp + r;
    if (node >= n) break;
#pragma unroll
    for (int g = 0; g < 4; ++g) {
      int col = g * 16 + colb;
      float hv = accH[g][r];
      __hip_bfloat16 hb = __float2bfloat16(hv);
      R[(size_t)node * 128 + col] = *(ushort_t*)&hb;
      Crh[(size_t)node * 64 + col] = __float2half(hv * csv[r]);
      Srh[(size_t)node * 64 + col] = __float2half(hv * snv[r]);
    }
    ushort_t* ap = (ushort_t*)(AdP + (size_t)node * 64);
#pragma unroll
    for (int g2 = 0; g2 < 2; ++g2) {
      int col = g2 * 16 + colb;
      __hip_bfloat16 ab = __float2bfloat16(accAd[g2][r]);
      ap[col] = *(ushort_t*)&ab;
      __hip_bfloat16 sb2 = __float2bfloat16(accAs[g2][r]);
      R[(size_t)node * 128 + 64 + col] = *(ushort_t*)&sb2;
    }
    if (colb == 0) {
      float* sp = (float*)(R + (size_t)node * 128 + 96);
      sp[0] = p1[r];
      sp[1] = p2[r];
      float* dp = AdP + (size_t)node * 64;
      dp[16] = p1[r];
      dp[17] = p2[r];
    }
  }
}

// ---- kPhaseTanh: blocks [0,1024) = lane-per-edge phase -> {s, half2(cos,sin)} recs;
//                  blocks [1024,1040) = p = tanh(z2@aw3+ab3)
__global__ __launch_bounds__(256) void kPhaseTanh(
    const int* __restrict__ ei, const float* __restrict__ ew, int ne,
    const ushort_t* __restrict__ R, const float* __restrict__ AdP,
    const float* __restrict__ C0G1, const float* __restrict__ w2,
    const float* __restrict__ b2,
    const unsigned* __restrict__ off, unsigned* __restrict__ cur,
    int2* __restrict__ recSC,
    const float* __restrict__ z2g, const float* __restrict__ aw3,
    const float* __restrict__ ab3, float* __restrict__ pG) {
  if (blockIdx.x >= 1024) {
    int rc = (blockIdx.x - 1024) * 256 + threadIdx.x;
    float a = ab3[rc];
    for (int m = 0; m < 64; ++m) a = fmaf(z2g[m], aw3[m * 4096 + rc], a);
    pG[rc] = tanhf(a);
    return;
  }
  const float b2r = b2[0];
  int t = blockIdx.x * 256 + threadIdx.x;
  int st = 1024 * 256;
  for (int e = t; e < ne; e += st) {
    int s = ei[e];
    int d = ei[ne + e];
    const ushort_t* rs = R + (size_t)s * 128;
    const float* bp = AdP + (size_t)d * 64;
    float2 ps = *(const float2*)(rs + 96);
    float2 pd = *(const float2*)(bp + 16);
    float meanE = (ps.x + pd.x) * 0.0078125f;
    float varE = fmaf(-meanE, meanE, (ps.y + pd.y) * 0.0078125f);
    float rstdE = rsqrtf(varE + 1e-5f);
    const uint4* asq = (const uint4*)(rs + 64);
    const uint4* adq = (const uint4*)bp;
    float z = b2r;
#pragma unroll
    for (int q = 0; q < 4; ++q) {
      uint4 ua = adq[q];
      uint4 ub = asq[q];
      unsigned av[4] = {ua.x, ua.y, ua.z, ua.w};
      unsigned bv[4] = {ub.x, ub.y, ub.z, ub.w};
#pragma unroll
      for (int p = 0; p < 4; ++p) {
        int k0 = q * 8 + p * 2;
        float a0 = __uint_as_float(av[p] << 16);
        float a1 = __uint_as_float(av[p] & 0xFFFF0000u);
        float b0 = __uint_as_float(bv[p] << 16);
        float b1 = __uint_as_float(bv[p] & 0xFFFF0000u);
        float pre0 = fmaf(rstdE, fmaf(-meanE, C0G1[32 + k0], a0 + b0), C0G1[k0]);
        float pre1 = fmaf(rstdE, fmaf(-meanE, C0G1[32 + k0 + 1], a1 + b1), C0G1[k0 + 1]);
        z = fmaf(fmaxf(pre0, 0.f), w2[k0], z);
        z = fmaf(fmaxf(pre1, 0.f), w2[k0 + 1], z);
      }
    }
    float coup = 1.f / (1.f + expf(-z));
    float cw = fminf(fmaxf(ew[e], 0.1f), 2.f);
    float ph = fminf(0.3f * coup * cw, MAXPH);
    float sn, cs;
    sincosf(ph, &sn, &cs);
    unsigned p = atomicAdd(&cur[d], 1u);
    unsigned pos = off[d] + p;
    __half2 h2 = __floats2half2_rn(cs, sn);
    int2 rec;
    rec.x = s;
    rec.y = *(int*)&h2;
    recSC[pos] = rec;
  }
}

// ---- kScatter: wave-per-node register-accumulate gather
__global__ __launch_bounds__(256) void kScatter(
    const unsigned* __restrict__ off, const int2* __restrict__ recSC,
    const ushort_t* __restrict__ R,
    __half* __restrict__ Crh, __half* __restrict__ Srh, int n) {
  const int lane = threadIdx.x & 63;
  const int wid = (blockIdx.x * blockDim.x + threadIdx.x) >> 6;
  const int nw = (gridDim.x * blockDim.x) >> 6;
  for (int d = wid; d < n; d += nw) {
    unsigned u0 = off[d], u1 = off[d + 1];
    float accR = 0.f, accI = 0.f;
    unsigned j = u0;
    for (; j + 8 <= u1; j += 8) {
      int s8[8];
      float2 c8[8];
#pragma unroll
      for (int k = 0; k < 8; ++k) {
        int2 rec = recSC[j + k];
        s8[k] = rec.x;
        __half2 h2 = *(__half2*)&rec.y;
        c8[k] = __half22float2(h2);
      }
#pragma unroll
      for (int k = 0; k < 8; ++k) {
        float hv = bf2f(R[(size_t)s8[k] * 128 + lane]);
        accR = fmaf(hv, c8[k].x, accR);
        accI = fmaf(hv, c8[k].y, accI);
      }
    }
    for (; j < u1; ++j) {
      int2 rec = recSC[j];
      __half2 h2 = *(__half2*)&rec.y;
      float2 c = __half22float2(h2);
      float hv = bf2f(R[(size_t)rec.x * 128 + lane]);
      accR = fmaf(hv, c.x, accR);
      accI = fmaf(hv, c.y, accI);
    }
    size_t idx = (size_t)d * 64 + lane;
    Crh[idx] = __float2half(__half2float(Crh[idx]) + accR);
    Srh[idx] = __float2half(__half2float(Srh[idx]) + accI);
  }
}

// ---- kExpm: single block — B from p (padded LDS), dynamic scaling, Taylor-6 + s squarings
__global__ __launch_bounds__(1024) void kExpm(const float* __restrict__ pG,
                                              float* __restrict__ UrT,
                                              float* __restrict__ UiT) {
  __shared__ float Br[64 * 65], Bi[64 * 65];
  __shared__ float Xr[64 * 68], Xi[64 * 68];
  __shared__ float rowsum[64];
  __shared__ int sSh;
  const int tid = threadIdx.x;
  const float SC0 = 0.05f;  // 0.1 * 0.5
  for (int idx = tid; idx < 4096; idx += 1024) {
    int r = idx >> 6, c = idx & 63;
    float pr = pG[r * 64 + c], pt = pG[c * 64 + r];
    Br[r * 65 + c] = (pr - pt) * SC0;
    Bi[r * 65 + c] = (pr + pt) * SC0;
  }
  __syncthreads();
  if (tid < 64) {
    float a = 0.f;
    for (int c = 0; c < 64; ++c) a += fabsf(Br[tid * 65 + c]) + fabsf(Bi[tid * 65 + c]);
    rowsum[tid] = a;
  }
  __syncthreads();
  if (tid == 0) {
    float m = 0.f;
    for (int i2 = 0; i2 < 64; ++i2) m = fmaxf(m, rowsum[i2]);
    int s = 0;
    while (m > 0.25f && s < 16) {
      m *= 0.5f;
      ++s;
    }
    sSh = s;
  }
  __syncthreads();
  const int sVal = sSh;
  const float scale = ldexpf(1.f, -sVal);
  for (int idx = tid; idx < 4096; idx += 1024) {
    int r = idx >> 6, c = idx & 63;
    float br = Br[r * 65 + c] * scale;
    float bi = Bi[r * 65 + c] * scale;
    Br[r * 65 + c] = br;
    Bi[r * 65 + c] = bi;
    Xr[r * 68 + c] = (r == c ? 1.f : 0.f) + br * (1.f / 6.f);
    Xi[r * 68 + c] = bi * (1.f / 6.f);
  }
  __syncthreads();
  const int i = tid >> 4, j0 = (tid & 15) << 2;
  for (int kk = 5; kk >= 1; --kk) {
    float ar[4] = {0, 0, 0, 0}, ai[4] = {0, 0, 0, 0};
    for (int m = 0; m < 64; ++m) {
      float br = Br[i * 65 + m], bi = Bi[i * 65 + m];
      float4 xr4 = *(const float4*)&Xr[m * 68 + j0];
      float4 xi4 = *(const float4*)&Xi[m * 68 + j0];
      float xr[4] = {xr4.x, xr4.y, xr4.z, xr4.w};
      float xi[4] = {xi4.x, xi4.y, xi4.z, xi4.w};
#pragma unroll
      for (int q = 0; q < 4; ++q) {
        ar[q] = fmaf(br, xr[q], fmaf(-bi, xi[q], ar[q]));
        ai[q] = fmaf(br, xi[q], fmaf(bi, xr[q], ai[q]));
      }
    }
    __syncthreads();
    float inv = 1.f / (float)kk;
#pragma unroll
    for (int q = 0; q < 4; ++q) {
      int c = j0 + q;
      Xr[i * 68 + c] = (i == c ? 1.f : 0.f) + ar[q] * inv;
      Xi[i * 68 + c] = ai[q] * inv;
    }
    __syncthreads();
  }
  for (int sq = 0; sq < sVal; ++sq) {
    float ar[4] = {0, 0, 0, 0}, ai[4] = {0, 0, 0, 0};
    for (int m = 0; m < 64; ++m) {
      float br = Xr[i * 68 + m], bi = Xi[i * 68 + m];
      float4 xr4 = *(const float4*)&Xr[m * 68 + j0];
      float4 xi4 = *(const float4*)&Xi[m * 68 + j0];
      float xr[4] = {xr4.x, xr4.y, xr4.z, xr4.w};
      float xi[4] = {xi4.x, xi4.y, xi4.z, xi4.w};
#pragma unroll
      for (int q = 0; q < 4; ++q) {
        ar[q] = fmaf(br, xr[q], fmaf(-bi, xi[q], ar[q]));
        ai[q] = fmaf(br, xi[q], fmaf(bi, xr[q], ai[q]));
      }
    }
    __syncthreads();
#pragma unroll
    for (int q = 0; q < 4; ++q) {
      Xr[i * 68 + j0 + q] = ar[q];
      Xi[i * 68 + j0 + q] = ai[q];
    }
    __syncthreads();
  }
  for (int idx = tid; idx < 4096; idx += 1024) {
    int a2 = idx >> 6, b2i = idx & 63;
    UrT[idx] = Xr[b2i * 68 + a2];
    UiT[idx] = Xi[b2i * 68 + a2];
  }
}

// ---- kFinalM: MFMA GEMM — OutR=[Cr|Sr]@[UrT;-UiT], OutI=[Cr|Sr]@[UiT;UrT]; +0.5*LN(x)
__global__ __launch_bounds__(256) void kFinalM(
    const float* __restrict__ x, const __half* __restrict__ Crh,
    const __half* __restrict__ Srh, const float* __restrict__ UrT,
    const float* __restrict__ UiT, float* __restrict__ out, int n, int ntiles) {
  __shared__ _Float16 bR[1024][8];
  __shared__ _Float16 bI[1024][8];
  __shared__ float xrT[4][16][65];
  const int tid = threadIdx.x;
  const int lane = tid & 63;
  const int wave = tid >> 6;
  for (int slot = tid; slot < 1024; slot += 256) {
    int g = slot >> 8;
    int c = (slot >> 6) & 3;
    int l = slot & 63;
    int col = g * 16 + (l & 15);
    int kb = c * 32 + ((l >> 4) << 3);
#pragma unroll
    for (int j = 0; j < 8; ++j) {
      int k = kb + j;
      float vr, vi;
      if (k < 64) {
        vr = UrT[k * 64 + col];
        vi = UiT[k * 64 + col];
      } else {
        vr = -UiT[(k - 64) * 64 + col];
        vi = UrT[(k - 64) * 64 + col];
      }
      bR[slot][j] = (_Float16)vr;
      bI[slot][j] = (_Float16)vi;
    }
  }
  __syncthreads();
  const int tile = blockIdx.x * 4 + wave;
  if (tile >= ntiles) return;
  const int base = tile << 4;
  for (int nn = 0; nn < 16; ++nn) {
    int node = min(base + nn, n - 1);
    float xv = x[(size_t)node * 64 + lane];
    float s1 = wsum64(xv);
    float s2 = wsum64(xv * xv);
    float mean = s1 * 0.015625f;
    float var = fmaf(-mean, mean, s2 * 0.015625f);
    xrT[wave][nn][lane] = (xv - mean) * rsqrtf(var + 1e-5f);
  }
  const int row = lane & 15;
  const int node = min(base + row, n - 1);
  const int kb = (lane >> 4) << 3;
  const _Float16* crp = (const _Float16*)(Crh + (size_t)node * 64);
  const _Float16* srp = (const _Float16*)(Srh + (size_t)node * 64);
  half8 a0 = *(const half8*)(crp + kb);
  half8 a1 = *(const half8*)(crp + 32 + kb);
  half8 a2 = *(const half8*)(srp + kb);
  half8 a3 = *(const half8*)(srp + 32 + kb);
  const size_t imag_off = (size_t)n * 64;
  const int rgrp = (lane >> 4) << 2;
#pragma unroll
  for (int g = 0; g < 4; ++g) {
    f32x4 accR = {0.f, 0.f, 0.f, 0.f};
    f32x4 accI = {0.f, 0.f, 0.f, 0.f};
    const int sb = g * 256 + lane;
    accR = __builtin_amdgcn_mfma_f32_16x16x32_f16(a0, *(const half8*)&bR[sb][0], accR, 0, 0, 0);
    accR = __builtin_amdgcn_mfma_f32_16x16x32_f16(a1, *(const half8*)&bR[sb + 64][0], accR, 0, 0, 0);
    accR = __builtin_amdgcn_mfma_f32_16x16x32_f16(a2, *(const half8*)&bR[sb + 128][0], accR, 0, 0, 0);
    accR = __builtin_amdgcn_mfma_f32_16x16x32_f16(a3, *(const half8*)&bR[sb + 192][0], accR, 0, 0, 0);
    accI = __builtin_amdgcn_mfma_f32_16x16x32_f16(a0, *(const half8*)&bI[sb][0], accI, 0, 0, 0);
    accI = __builtin_amdgcn_mfma_f32_16x16x32_f16(a1, *(const half8*)&bI[sb + 64][0], accI, 0, 0, 0);
    accI = __builtin_amdgcn_mfma_f32_16x16x32_f16(a2, *(const half8*)&bI[sb + 128][0], accI, 0, 0, 0);
    accI = __builtin_amdgcn_mfma_f32_16x16x32_f16(a3, *(const half8*)&bI[sb + 192][0], accI, 0, 0, 0);
    const int col = g * 16 + (lane & 15);
#pragma unroll
    for (int reg = 0; reg < 4; ++reg) {
      int r = base + rgrp + reg;
      if (r < n) {
        out[(size_t)r * 64 + col] = 0.5f * (accR[reg] + xrT[wave][rgrp + reg][col]);
        out[imag_off + (size_t)r * 64 + col] = 0.5f * accI[reg];
      }
    }
  }
}

extern "C" void kernel_launch(void* const* d_in, const int* in_sizes, int n_in,
                              void* d_out, int out_size, void* d_ws, size_t ws_size,
                              hipStream_t stream) {
  const float* x    = (const float*)d_in[0];
  const int*   ei   = (const int*)d_in[1];
  const float* ew   = (const float*)d_in[2];
  const float* Wr   = (const float*)d_in[3];
  const float* ln_g = (const float*)d_in[5];
  const float* ln_b = (const float*)d_in[6];
  const float* w1   = (const float*)d_in[7];
  const float* b1   = (const float*)d_in[8];
  const float* w2   = (const float*)d_in[9];
  const float* b2   = (const float*)d_in[10];
  const float* g1w  = (const float*)d_in[11];
  const float* g1b  = (const float*)d_in[12];
  const float* g2w  = (const float*)d_in[13];
  const float* g2b  = (const float*)d_in[14];
  const float* aw1  = (const float*)d_in[15];
  const float* ab1  = (const float*)d_in[16];
  const float* aw2  = (const float*)d_in[17];
  const float* ab2  = (const float*)d_in[18];
  const float* aw3  = (const float*)d_in[19];
  const float* ab3  = (const float*)d_in[20];
  const int n = in_sizes[0] / 64;
  const int e = in_sizes[1] / 2;
  float* out = (float*)d_out;

  float* ws = (float*)d_ws;
  float* Wg1  = ws;                           // 4096
  float* C0G1 = ws + 4096;                    // 64
  float* UrT  = ws + 4160;                    // 4096
  float* UiT  = ws + 8256;                    // 4096
  float* z2g  = ws + 12352;                   // 64
  float* pG   = ws + 12416;                   // 4096
  unsigned* AdjU = (unsigned*)(ws + 20544);   // 4096 u32 (zero region start)
  unsigned* cnt = AdjU + 4096;                // n
  unsigned* cur = cnt + n;                    // n
  unsigned* off = cur + n;                    // n+1 (fully written by scan)
  size_t p0 = (20544 + 4096 + 3 * (size_t)n + 1 + 63) & ~(size_t)63;
  int2* recSC = (int2*)(ws + p0);             // e int2
  size_t p2 = (p0 + 2 * (size_t)e + 63) & ~(size_t)63;
  ushort_t* R = (ushort_t*)(ws + p2);         // 64n f32-units
  size_t p3 = (p2 + 64 * (size_t)n + 63) & ~(size_t)63;
  float* AdP = ws + p3;                       // 64n f32-units
  size_t p4 = (p3 + 64 * (size_t)n + 63) & ~(size_t)63;
  __half* Crh = (__half*)(ws + p4);           // 32n
  size_t p5 = (p4 + 32 * (size_t)n + 63) & ~(size_t)63;
  __half* Srh = (__half*)(ws + p5);           // 32n

  const int ntiles = (n + 15) >> 4;
  const int nb = (ntiles + 3) >> 2;

  hipMemsetAsync(AdjU, 0, (4096 + 2 * (size_t)n) * 4, stream);
  kCountPrep<<<1025, 256, 0, stream>>>(ei, e, cnt, AdjU, ln_g, ln_b, w1, b1, Wg1, C0G1);
  kNodeMSG<<<nb + 2, 256, 0, stream>>>(x, Wr, Wg1, C0G1, w2, b2, R, AdP, Crh, Srh, n, ntiles,
                                       nb, cnt, off, AdjU, g1w, g1b, g2w, g2b,
                                       aw1, ab1, aw2, ab2, z2g);
  kPhaseTanh<<<1040, 256, 0, stream>>>(ei, ew, e, R, AdP, C0G1, w2, b2, off, cur, recSC,
                                       z2g, aw3, ab3, pG);
  kScatter<<<2048, 256, 0, stream>>>(off, recSC, R, Crh, Srh, n);
  kExpm<<<1, 1024, 0, stream>>>(pG, UrT, UiT);
  kFinalM<<<nb, 256, 0, stream>>>(x, Crh, Srh, UrT, UiT, out, n, ntiles);
}

// Round 21
// 330.231 us; speedup vs baseline: 1.0041x; 1.0041x over previous
//
#include <hip/hip_runtime.h>
#include <hip/hip_bf16.h>
#include <hip/hip_fp16.h>

#define MAXPH 0.78539816339744831f
typedef unsigned short ushort_t;
typedef _Float16 half8 __attribute__((ext_vector_type(8)));
typedef float f32x4 __attribute__((ext_vector_type(4)));

__device__ __forceinline__ float wsum64(float v) {
#pragma unroll
  for (int o = 32; o > 0; o >>= 1) v += __shfl_xor(v, o);
  return v;
}
__device__ __forceinline__ float bf2f(ushort_t u) {
  return __uint_as_float(((unsigned)u) << 16);
}

// ---- kCountPrep: blocks [0,1024) = per-dst histogram + AdjU; block 1024 = prep Wg1/C0G1
__global__ __launch_bounds__(256) void kCountPrep(
    const int* __restrict__ ei, int ne, unsigned* __restrict__ cnt,
    unsigned* __restrict__ AdjU,
    const float* __restrict__ ln_g, const float* __restrict__ ln_b,
    const float* __restrict__ w1, const float* __restrict__ b1,
    float* __restrict__ Wg1, float* __restrict__ C0G1) {
  if (blockIdx.x < 1024) {
    int t = blockIdx.x * 256 + threadIdx.x;
    int st = 1024 * 256;
    for (int e = t; e < ne; e += st) {
      int s = ei[e];
      int d = ei[ne + e];
      atomicAdd(&cnt[d], 1u);
      if ((unsigned)(s | d) < 64u) atomicAdd(&AdjU[d * 64 + s], 1u);
    }
  } else {
    int tt = threadIdx.x;
    for (int idx = tt; idx < 4096; idx += 256) {
      int j = idx >> 5;
      Wg1[idx] = ln_g[j] * w1[idx];
    }
    if (tt < 32) {
      float c0 = b1[tt], g1 = 0.f;
      for (int j = 0; j < 128; ++j) {
        float w = w1[j * 32 + tt];
        c0 = fmaf(ln_b[j], w, c0);
        g1 = fmaf(ln_g[j], w, g1);
      }
      C0G1[tt] = c0;
      C0G1[32 + tt] = g1;
    }
  }
}

// ---- kNodeMSG2: blocks [0,nb) = MFMA node; block nb = coalesced scan; nb+1 = GCN (parallelized)
__global__ __launch_bounds__(256) void kNodeMSG2(
    const float* __restrict__ x, const float* __restrict__ Wr,
    const float* __restrict__ Wg1, const float* __restrict__ C0G1,
    const float* __restrict__ w2, const float* __restrict__ b2,
    ushort_t* __restrict__ R, float* __restrict__ AdP,
    __half* __restrict__ Crh, __half* __restrict__ Srh, int n, int ntiles, int nb,
    const unsigned* __restrict__ cnt, unsigned* __restrict__ off,
    const unsigned* __restrict__ AdjU,
    const float* __restrict__ g1w, const float* __restrict__ g1b,
    const float* __restrict__ g2w, const float* __restrict__ g2b,
    const float* __restrict__ aw1, const float* __restrict__ ab1,
    const float* __restrict__ aw2, const float* __restrict__ ab2,
    float* __restrict__ z2g) {
  __shared__ float SHF[8832];  // 35328 B union
  const int tid = threadIdx.x;
  const int bid = blockIdx.x;

  if (bid == nb) {
    // ======== coalesced 2-pass exclusive scan (4 waves × contiguous quarter) ========
    unsigned* wsums = (unsigned*)SHF;
    const int w = tid >> 6, l = tid & 63;
    const int chunk = (n + 3) >> 2;
    const int lo = w * chunk;
    const int hi = min(lo + chunk, n);
    unsigned s = 0;
    for (int i = lo + l; i < hi; i += 64) s += cnt[i];
#pragma unroll
    for (int o = 32; o > 0; o >>= 1) s += __shfl_xor(s, o);
    if (l == 0) wsums[w] = s;
    __syncthreads();
    unsigned base = 0;
    for (int i = 0; i < w; ++i) base += wsums[i];
    for (int i0 = lo; i0 < hi; i0 += 64) {
      int i = i0 + l;
      unsigned v = (i < hi) ? cnt[i] : 0u;
      unsigned inc = v;
#pragma unroll
      for (int o = 1; o < 64; o <<= 1) {
        unsigned u = __shfl_up(inc, o);
        if (l >= o) inc += u;
      }
      if (i < hi) off[i] = base + inc - v;
      base += __shfl(inc, 63);
    }
    if (w == 3 && l == 63) off[n] = base;
    return;
  }
  if (bid == nb + 1) {
    // ======== GCN x2 + pool + MLP -> z2 (256 threads, fully parallel reductions) ========
    float* L0 = SHF;                 // 4160
    float* L1 = SHF + 4160;          // 4160
    float* sdv = SHF + 8320;         // 64
    float* sts = sdv + 64;           // 64
    float* sgp = sts + 64;           // 64
    float* sz1 = sgp + 64;           // 64
    float* part = sz1 + 64;          // 256
    const int kk6 = tid & 63, mq = tid >> 6;
    for (int idx = tid; idx < 4096; idx += 256) {
      int r = idx >> 6, c = idx & 63;
      L0[r * 65 + c] = (float)AdjU[idx];
    }
    __syncthreads();
    {  // deg (row sums)
      float p = 0.f;
      for (int c = mq * 16; c < mq * 16 + 16; ++c) p += L0[kk6 * 65 + c];
      part[mq * 64 + kk6] = p;
    }
    __syncthreads();
    if (tid < 64)
      sdv[tid] = rsqrtf(1.f + part[tid] + part[64 + tid] + part[128 + tid] + part[192 + tid]);
    __syncthreads();
    {  // sts = sum_c L0[r][c]*dv[c]
      float p = 0.f;
      for (int c = mq * 16; c < mq * 16 + 16; ++c) p += L0[kk6 * 65 + c] * sdv[c];
      part[mq * 64 + kk6] = p;
    }
    __syncthreads();
    if (tid < 64) sts[tid] = part[tid] + part[64 + tid] + part[128 + tid] + part[192 + tid];
    __syncthreads();
    for (int idx = tid; idx < 4096; idx += 256) {
      int d = idx >> 6, c = idx & 63;
      L1[d * 65 + c] = fmaxf(fmaf(g1w[c], fmaf(sts[d], sdv[d], sdv[d] * sdv[d]), g1b[c]), 0.f);
    }
    __syncthreads();
    const int i2 = tid >> 2, j0 = (tid & 3) << 4;
    float xw[16];
#pragma unroll
    for (int q = 0; q < 16; ++q) xw[q] = 0.f;
    for (int m = 0; m < 64; ++m) {
      float hm = L1[i2 * 65 + m];
      const float* wp = g2w + m * 64 + j0;
#pragma unroll
      for (int q = 0; q < 16; ++q) xw[q] = fmaf(hm, wp[q], xw[q]);
    }
    __syncthreads();
#pragma unroll
    for (int q = 0; q < 16; ++q) L1[i2 * 65 + j0 + q] = xw[q];
    __syncthreads();
    float a[16];
#pragma unroll
    for (int q = 0; q < 16; ++q) a[q] = 0.f;
    for (int s2 = 0; s2 < 64; ++s2) {
      float wv = L0[i2 * 65 + s2] * sdv[s2];
#pragma unroll
      for (int q = 0; q < 16; ++q) a[q] = fmaf(wv, L1[s2 * 65 + j0 + q], a[q]);
    }
    float di = sdv[i2], sc = di * di;
    float h2v[16];
#pragma unroll
    for (int q = 0; q < 16; ++q)
      h2v[q] = fmaf(a[q], di, fmaf(sc, L1[i2 * 65 + j0 + q], g2b[j0 + q]));
    __syncthreads();
#pragma unroll
    for (int q = 0; q < 16; ++q) L1[i2 * 65 + j0 + q] = h2v[q];
    __syncthreads();
    {  // pool: column sums / 64
      float p = 0.f;
      for (int r = mq * 16; r < mq * 16 + 16; ++r) p += L1[r * 65 + kk6];
      part[mq * 64 + kk6] = p;
    }
    __syncthreads();
    if (tid < 64)
      sgp[tid] = (part[tid] + part[64 + tid] + part[128 + tid] + part[192 + tid]) * 0.015625f;
    __syncthreads();
    {  // z1[k] = relu(ab1[k] + sum_m gp[m]*aw1[m*64+k]) — coalesced over k
      float p = 0.f;
      for (int m = mq * 16; m < mq * 16 + 16; ++m) p = fmaf(sgp[m], aw1[m * 64 + kk6], p);
      part[mq * 64 + kk6] = p;
    }
    __syncthreads();
    if (tid < 64)
      sz1[tid] = fmaxf(ab1[tid] + part[tid] + part[64 + tid] + part[128 + tid] + part[192 + tid], 0.f);
    __syncthreads();
    {  // z2
      float p = 0.f;
      for (int m = mq * 16; m < mq * 16 + 16; ++m) p = fmaf(sz1[m], aw2[m * 64 + kk6], p);
      part[mq * 64 + kk6] = p;
    }
    __syncthreads();
    if (tid < 64)
      z2g[tid] = fmaxf(ab2[tid] + part[tid] + part[64 + tid] + part[128 + tid] + part[192 + tid], 0.f);
    return;
  }

  // ======== node MFMA path ========
  _Float16* bWr = (_Float16*)SHF;
  _Float16* bAd = (_Float16*)(SHF + 2048);
  _Float16* bAs = (_Float16*)(SHF + 3072);
  _Float16* cmT = (_Float16*)(SHF + 4096);
  const int lane = tid & 63;
  const int wave = tid >> 6;
  for (int slot = tid; slot < 512; slot += 256) {
    int g = slot >> 7;
    int c = (slot >> 6) & 1;
    int l = slot & 63;
    int col = g * 16 + (l & 15);
    int kb0 = c * 32 + ((l >> 4) << 3);
#pragma unroll
    for (int j = 0; j < 8; ++j) bWr[slot * 8 + j] = (_Float16)Wr[(kb0 + j) * 64 + col];
  }
  {
    int slot = tid;
    int g2 = slot >> 7;
    int c = (slot >> 6) & 1;
    int l = slot & 63;
    int col = g2 * 16 + (l & 15);
    int kb0 = c * 32 + ((l >> 4) << 3);
#pragma unroll
    for (int j = 0; j < 8; ++j) {
      bAd[slot * 8 + j] = (_Float16)Wg1[(kb0 + j) * 32 + col];
      bAs[slot * 8 + j] = (_Float16)Wg1[(64 + kb0 + j) * 32 + col];
    }
  }
  __syncthreads();
  const int tile = bid * 4 + wave;
  if (tile >= ntiles) return;
  const int base = tile << 4;
  const int row = lane & 15;
  const int kb = (lane >> 4) << 3;
  const int nodeA = min(base + row, n - 1);
  const float* xp = x + (size_t)nodeA * 64;
  float xv[8], xh[8];
  *(float4*)&xv[0] = *(const float4*)(xp + kb);
  *(float4*)&xv[4] = *(const float4*)(xp + kb + 4);
  *(float4*)&xh[0] = *(const float4*)(xp + 32 + kb);
  *(float4*)&xh[4] = *(const float4*)(xp + 32 + kb + 4);
  float s1 = 0.f, s2 = 0.f;
#pragma unroll
  for (int j = 0; j < 8; ++j) {
    s1 += xv[j] + xh[j];
    s2 += xv[j] * xv[j] + xh[j] * xh[j];
  }
  s1 += __shfl_xor(s1, 16);
  s1 += __shfl_xor(s1, 32);
  s2 += __shfl_xor(s2, 16);
  s2 += __shfl_xor(s2, 32);
  float mean = s1 * 0.015625f;
  float var = fmaf(-mean, mean, s2 * 0.015625f);
  float rstd = rsqrtf(var + 1e-5f);
  half8 aLo, aHi;
#pragma unroll
  for (int j = 0; j < 8; ++j) {
    aLo[j] = (_Float16)((xv[j] - mean) * rstd);
    aHi[j] = (_Float16)((xh[j] - mean) * rstd);
  }
  f32x4 accH[4];
#pragma unroll
  for (int g = 0; g < 4; ++g) {
    f32x4 z4 = {0.f, 0.f, 0.f, 0.f};
    z4 = __builtin_amdgcn_mfma_f32_16x16x32_f16(aLo, *(const half8*)&bWr[(g * 128 + lane) * 8], z4, 0, 0, 0);
    z4 = __builtin_amdgcn_mfma_f32_16x16x32_f16(aHi, *(const half8*)&bWr[(g * 128 + 64 + lane) * 8], z4, 0, 0, 0);
    accH[g] = z4;
  }
  float cm[4][4];
  float p1[4] = {0.f, 0.f, 0.f, 0.f}, p2[4] = {0.f, 0.f, 0.f, 0.f};
#pragma unroll
  for (int g = 0; g < 4; ++g)
#pragma unroll
    for (int r = 0; r < 4; ++r) {
      float hv = accH[g][r];
      float m = fminf(sqrtf(fmaf(hv, hv, 1e-8f)), 10.f);
      cm[g][r] = m;
      p1[r] += m;
      p2[r] += m * m;
    }
#pragma unroll
  for (int o = 1; o <= 8; o <<= 1)
#pragma unroll
    for (int r = 0; r < 4; ++r) {
      p1[r] += __shfl_xor(p1[r], o);
      p2[r] += __shfl_xor(p2[r], o);
    }
  const int rgrp = (lane >> 4) << 2;
#pragma unroll
  for (int g = 0; g < 4; ++g)
#pragma unroll
    for (int r = 0; r < 4; ++r)
      cmT[((wave * 16) + rgrp + r) * 72 + g * 16 + (lane & 15)] = (_Float16)cm[g][r];
  half8 cLo = *(const half8*)&cmT[((wave * 16) + row) * 72 + kb];
  half8 cHi = *(const half8*)&cmT[((wave * 16) + row) * 72 + 32 + kb];
  f32x4 accAd[2], accAs[2];
#pragma unroll
  for (int g2 = 0; g2 < 2; ++g2) {
    f32x4 z4 = {0.f, 0.f, 0.f, 0.f};
    z4 = __builtin_amdgcn_mfma_f32_16x16x32_f16(cLo, *(const half8*)&bAd[(g2 * 128 + lane) * 8], z4, 0, 0, 0);
    z4 = __builtin_amdgcn_mfma_f32_16x16x32_f16(cHi, *(const half8*)&bAd[(g2 * 128 + 64 + lane) * 8], z4, 0, 0, 0);
    accAd[g2] = z4;
    f32x4 w4 = {0.f, 0.f, 0.f, 0.f};
    w4 = __builtin_amdgcn_mfma_f32_16x16x32_f16(cLo, *(const half8*)&bAs[(g2 * 128 + lane) * 8], w4, 0, 0, 0);
    w4 = __builtin_amdgcn_mfma_f32_16x16x32_f16(cHi, *(const half8*)&bAs[(g2 * 128 + 64 + lane) * 8], w4, 0, 0, 0);
    accAs[g2] = w4;
  }
  const float b2r = b2[0];
  float c0v[2], g1v[2], w2v[2];
#pragma unroll
  for (int g2 = 0; g2 < 2; ++g2) {
    int k = g2 * 16 + (lane & 15);
    c0v[g2] = C0G1[k];
    g1v[g2] = C0G1[32 + k];
    w2v[g2] = w2[k];
  }
  float zp[4];
#pragma unroll
  for (int r = 0; r < 4; ++r) {
    float meanE = p1[r] * 0.015625f;
    float varE = fmaf(-meanE, meanE, p2[r] * 0.015625f);
    float rstdE = rsqrtf(varE + 1e-5f);
    float zz = 0.f;
#pragma unroll
    for (int g2 = 0; g2 < 2; ++g2) {
      float pre = fmaf(rstdE, fmaf(-meanE, g1v[g2], accAd[g2][r] + accAs[g2][r]), c0v[g2]);
      zz = fmaf(fmaxf(pre, 0.f), w2v[g2], zz);
    }
    zp[r] = zz;
  }
#pragma unroll
  for (int o = 1; o <= 8; o <<= 1)
#pragma unroll
    for (int r = 0; r < 4; ++r) zp[r] += __shfl_xor(zp[r], o);
  float csv[4], snv[4];
#pragma unroll
  for (int r = 0; r < 4; ++r) {
    float coup = 1.f / (1.f + expf(-(zp[r] + b2r)));
    float ph = fminf(0.3f * coup, MAXPH);
    sincosf(ph, &snv[r], &csv[r]);
  }
  const int colb = lane & 15;
#pragma unroll
  for (int r = 0; r < 4; ++r) {
    int node = base + rgrp + r;
    if (node >= n) break;
#pragma unroll
    for (int g = 0; g < 4; ++g) {
      int col = g * 16 + colb;
      float hv = accH[g][r];
      __hip_bfloat16 hb = __float2bfloat16(hv);
      R[(size_t)node * 128 + col] = *(ushort_t*)&hb;
      Crh[(size_t)node * 64 + col] = __float2half(hv * csv[r]);
      Srh[(size_t)node * 64 + col] = __float2half(hv * snv[r]);
    }
    ushort_t* ap = (ushort_t*)(AdP + (size_t)node * 64);
#pragma unroll
    for (int g2 = 0; g2 < 2; ++g2) {
      int col = g2 * 16 + colb;
      __hip_bfloat16 ab = __float2bfloat16(accAd[g2][r]);
      ap[col] = *(ushort_t*)&ab;
      __hip_bfloat16 sb2 = __float2bfloat16(accAs[g2][r]);
      R[(size_t)node * 128 + 64 + col] = *(ushort_t*)&sb2;
    }
    if (colb == 0) {
      float* sp = (float*)(R + (size_t)node * 128 + 96);
      sp[0] = p1[r];
      sp[1] = p2[r];
      float* dp = AdP + (size_t)node * 64;
      dp[16] = p1[r];
      dp[17] = p2[r];
    }
  }
}

// ---- kPhaseTanh: blocks [0,1024) = lane-per-edge phase -> recs; [1024,1040) = tanh
__global__ __launch_bounds__(256) void kPhaseTanh(
    const int* __restrict__ ei, const float* __restrict__ ew, int ne,
    const ushort_t* __restrict__ R, const float* __restrict__ AdP,
    const float* __restrict__ C0G1, const float* __restrict__ w2,
    const float* __restrict__ b2,
    const unsigned* __restrict__ off, unsigned* __restrict__ cur,
    int2* __restrict__ recSC,
    const float* __restrict__ z2g, const float* __restrict__ aw3,
    const float* __restrict__ ab3, float* __restrict__ pG) {
  if (blockIdx.x >= 1024) {
    int rc = (blockIdx.x - 1024) * 256 + threadIdx.x;
    float a = ab3[rc];
    for (int m = 0; m < 64; ++m) a = fmaf(z2g[m], aw3[m * 4096 + rc], a);
    pG[rc] = tanhf(a);
    return;
  }
  const float b2r = b2[0];
  int t = blockIdx.x * 256 + threadIdx.x;
  int st = 1024 * 256;
  for (int e = t; e < ne; e += st) {
    int s = ei[e];
    int d = ei[ne + e];
    const ushort_t* rs = R + (size_t)s * 128;
    const float* bp = AdP + (size_t)d * 64;
    float2 ps = *(const float2*)(rs + 96);
    float2 pd = *(const float2*)(bp + 16);
    float meanE = (ps.x + pd.x) * 0.0078125f;
    float varE = fmaf(-meanE, meanE, (ps.y + pd.y) * 0.0078125f);
    float rstdE = rsqrtf(varE + 1e-5f);
    const uint4* asq = (const uint4*)(rs + 64);
    const uint4* adq = (const uint4*)bp;
    float z = b2r;
#pragma unroll
    for (int q = 0; q < 4; ++q) {
      uint4 ua = adq[q];
      uint4 ub = asq[q];
      unsigned av[4] = {ua.x, ua.y, ua.z, ua.w};
      unsigned bv[4] = {ub.x, ub.y, ub.z, ub.w};
#pragma unroll
      for (int p = 0; p < 4; ++p) {
        int k0 = q * 8 + p * 2;
        float a0 = __uint_as_float(av[p] << 16);
        float a1 = __uint_as_float(av[p] & 0xFFFF0000u);
        float b0 = __uint_as_float(bv[p] << 16);
        float b1 = __uint_as_float(bv[p] & 0xFFFF0000u);
        float pre0 = fmaf(rstdE, fmaf(-meanE, C0G1[32 + k0], a0 + b0), C0G1[k0]);
        float pre1 = fmaf(rstdE, fmaf(-meanE, C0G1[32 + k0 + 1], a1 + b1), C0G1[k0 + 1]);
        z = fmaf(fmaxf(pre0, 0.f), w2[k0], z);
        z = fmaf(fmaxf(pre1, 0.f), w2[k0 + 1], z);
      }
    }
    float coup = 1.f / (1.f + expf(-z));
    float cw = fminf(fmaxf(ew[e], 0.1f), 2.f);
    float ph = fminf(0.3f * coup * cw, MAXPH);
    float sn, cs;
    sincosf(ph, &sn, &cs);
    unsigned p = atomicAdd(&cur[d], 1u);
    unsigned pos = off[d] + p;
    __half2 h2 = __floats2half2_rn(cs, sn);
    int2 rec;
    rec.x = s;
    rec.y = *(int*)&h2;
    recSC[pos] = rec;
  }
}

// ---- kScatterExpm: blocks [0,G-1) = wave-per-node gather; block G-1 = expm (1024 thr)
__global__ __launch_bounds__(1024) void kScatterExpm(
    const unsigned* __restrict__ off, const int2* __restrict__ recSC,
    const ushort_t* __restrict__ R,
    __half* __restrict__ Crh, __half* __restrict__ Srh, int n,
    const float* __restrict__ pG, float* __restrict__ UrT, float* __restrict__ UiT) {
  __shared__ float Br[64 * 65], Bi[64 * 65];
  __shared__ float Xr[64 * 68], Xi[64 * 68];
  __shared__ float rowsum[64];
  __shared__ int sSh;
  const int tid = threadIdx.x;
  if (blockIdx.x == gridDim.x - 1) {
    // ======== expm ========
    const float SC0 = 0.05f;  // 0.1 * 0.5
    for (int idx = tid; idx < 4096; idx += 1024) {
      int r = idx >> 6, c = idx & 63;
      float pr = pG[r * 64 + c], pt = pG[c * 64 + r];
      Br[r * 65 + c] = (pr - pt) * SC0;
      Bi[r * 65 + c] = (pr + pt) * SC0;
    }
    __syncthreads();
    if (tid < 64) {
      float a = 0.f;
      for (int c = 0; c < 64; ++c) a += fabsf(Br[tid * 65 + c]) + fabsf(Bi[tid * 65 + c]);
      rowsum[tid] = a;
    }
    __syncthreads();
    if (tid == 0) {
      float m = 0.f;
      for (int i2 = 0; i2 < 64; ++i2) m = fmaxf(m, rowsum[i2]);
      int s = 0;
      while (m > 0.25f && s < 16) {
        m *= 0.5f;
        ++s;
      }
      sSh = s;
    }
    __syncthreads();
    const int sVal = sSh;
    const float scale = ldexpf(1.f, -sVal);
    for (int idx = tid; idx < 4096; idx += 1024) {
      int r = idx >> 6, c = idx & 63;
      float br = Br[r * 65 + c] * scale;
      float bi = Bi[r * 65 + c] * scale;
      Br[r * 65 + c] = br;
      Bi[r * 65 + c] = bi;
      Xr[r * 68 + c] = (r == c ? 1.f : 0.f) + br * (1.f / 6.f);
      Xi[r * 68 + c] = bi * (1.f / 6.f);
    }
    __syncthreads();
    const int i = tid >> 4, j0 = (tid & 15) << 2;
    for (int kk = 5; kk >= 1; --kk) {
      float ar[4] = {0, 0, 0, 0}, ai[4] = {0, 0, 0, 0};
      for (int m = 0; m < 64; ++m) {
        float br = Br[i * 65 + m], bi = Bi[i * 65 + m];
        float4 xr4 = *(const float4*)&Xr[m * 68 + j0];
        float4 xi4 = *(const float4*)&Xi[m * 68 + j0];
        float xr[4] = {xr4.x, xr4.y, xr4.z, xr4.w};
        float xi[4] = {xi4.x, xi4.y, xi4.z, xi4.w};
#pragma unroll
        for (int q = 0; q < 4; ++q) {
          ar[q] = fmaf(br, xr[q], fmaf(-bi, xi[q], ar[q]));
          ai[q] = fmaf(br, xi[q], fmaf(bi, xr[q], ai[q]));
        }
      }
      __syncthreads();
      float inv = 1.f / (float)kk;
#pragma unroll
      for (int q = 0; q < 4; ++q) {
        int c = j0 + q;
        Xr[i * 68 + c] = (i == c ? 1.f : 0.f) + ar[q] * inv;
        Xi[i * 68 + c] = ai[q] * inv;
      }
      __syncthreads();
    }
    for (int sq = 0; sq < sVal; ++sq) {
      float ar[4] = {0, 0, 0, 0}, ai[4] = {0, 0, 0, 0};
      for (int m = 0; m < 64; ++m) {
        float br = Xr[i * 68 + m], bi = Xi[i * 68 + m];
        float4 xr4 = *(const float4*)&Xr[m * 68 + j0];
        float4 xi4 = *(const float4*)&Xi[m * 68 + j0];
        float xr[4] = {xr4.x, xr4.y, xr4.z, xr4.w};
        float xi[4] = {xi4.x, xi4.y, xi4.z, xi4.w};
#pragma unroll
        for (int q = 0; q < 4; ++q) {
          ar[q] = fmaf(br, xr[q], fmaf(-bi, xi[q], ar[q]));
          ai[q] = fmaf(br, xi[q], fmaf(bi, xr[q], ai[q]));
        }
      }
      __syncthreads();
#pragma unroll
      for (int q = 0; q < 4; ++q) {
        Xr[i * 68 + j0 + q] = ar[q];
        Xi[i * 68 + j0 + q] = ai[q];
      }
      __syncthreads();
    }
    for (int idx = tid; idx < 4096; idx += 1024) {
      int a2 = idx >> 6, b2i = idx & 63;
      UrT[idx] = Xr[b2i * 68 + a2];
      UiT[idx] = Xi[b2i * 68 + a2];
    }
    return;
  }
  // ======== scatter ========
  const int lane = tid & 63;
  const int wid = (blockIdx.x * 1024 + tid) >> 6;
  const int nw = ((gridDim.x - 1) * 1024) >> 6;
  for (int d = wid; d < n; d += nw) {
    unsigned u0 = off[d], u1 = off[d + 1];
    float accR = 0.f, accI = 0.f;
    unsigned j = u0;
    for (; j + 8 <= u1; j += 8) {
      int s8[8];
      float2 c8[8];
#pragma unroll
      for (int k = 0; k < 8; ++k) {
        int2 rec = recSC[j + k];
        s8[k] = rec.x;
        __half2 h2 = *(__half2*)&rec.y;
        c8[k] = __half22float2(h2);
      }
#pragma unroll
      for (int k = 0; k < 8; ++k) {
        float hv = bf2f(R[(size_t)s8[k] * 128 + lane]);
        accR = fmaf(hv, c8[k].x, accR);
        accI = fmaf(hv, c8[k].y, accI);
      }
    }
    for (; j < u1; ++j) {
      int2 rec = recSC[j];
      __half2 h2 = *(__half2*)&rec.y;
      float2 c = __half22float2(h2);
      float hv = bf2f(R[(size_t)rec.x * 128 + lane]);
      accR = fmaf(hv, c.x, accR);
      accI = fmaf(hv, c.y, accI);
    }
    size_t idx = (size_t)d * 64 + lane;
    Crh[idx] = __float2half(__half2float(Crh[idx]) + accR);
    Srh[idx] = __float2half(__half2float(Srh[idx]) + accI);
  }
}

// ---- kFinalM: MFMA GEMM — OutR=[Cr|Sr]@[UrT;-UiT], OutI=[Cr|Sr]@[UiT;UrT]; +0.5*LN(x)
__global__ __launch_bounds__(256) void kFinalM(
    const float* __restrict__ x, const __half* __restrict__ Crh,
    const __half* __restrict__ Srh, const float* __restrict__ UrT,
    const float* __restrict__ UiT, float* __restrict__ out, int n, int ntiles) {
  __shared__ _Float16 bR[1024][8];
  __shared__ _Float16 bI[1024][8];
  __shared__ float xrT[4][16][65];
  const int tid = threadIdx.x;
  const int lane = tid & 63;
  const int wave = tid >> 6;
  for (int slot = tid; slot < 1024; slot += 256) {
    int g = slot >> 8;
    int c = (slot >> 6) & 3;
    int l = slot & 63;
    int col = g * 16 + (l & 15);
    int kb = c * 32 + ((l >> 4) << 3);
#pragma unroll
    for (int j = 0; j < 8; ++j) {
      int k = kb + j;
      float vr, vi;
      if (k < 64) {
        vr = UrT[k * 64 + col];
        vi = UiT[k * 64 + col];
      } else {
        vr = -UiT[(k - 64) * 64 + col];
        vi = UrT[(k - 64) * 64 + col];
      }
      bR[slot][j] = (_Float16)vr;
      bI[slot][j] = (_Float16)vi;
    }
  }
  __syncthreads();
  const int tile = blockIdx.x * 4 + wave;
  if (tile >= ntiles) return;
  const int base = tile << 4;
  for (int nn = 0; nn < 16; ++nn) {
    int node = min(base + nn, n - 1);
    float xv = x[(size_t)node * 64 + lane];
    float s1 = wsum64(xv);
    float s2 = wsum64(xv * xv);
    float mean = s1 * 0.015625f;
    float var = fmaf(-mean, mean, s2 * 0.015625f);
    xrT[wave][nn][lane] = (xv - mean) * rsqrtf(var + 1e-5f);
  }
  const int row = lane & 15;
  const int node = min(base + row, n - 1);
  const int kb = (lane >> 4) << 3;
  const _Float16* crp = (const _Float16*)(Crh + (size_t)node * 64);
  const _Float16* srp = (const _Float16*)(Srh + (size_t)node * 64);
  half8 a0 = *(const half8*)(crp + kb);
  half8 a1 = *(const half8*)(crp + 32 + kb);
  half8 a2 = *(const half8*)(srp + kb);
  half8 a3 = *(const half8*)(srp + 32 + kb);
  const size_t imag_off = (size_t)n * 64;
  const int rgrp = (lane >> 4) << 2;
#pragma unroll
  for (int g = 0; g < 4; ++g) {
    f32x4 accR = {0.f, 0.f, 0.f, 0.f};
    f32x4 accI = {0.f, 0.f, 0.f, 0.f};
    const int sb = g * 256 + lane;
    accR = __builtin_amdgcn_mfma_f32_16x16x32_f16(a0, *(const half8*)&bR[sb][0], accR, 0, 0, 0);
    accR = __builtin_amdgcn_mfma_f32_16x16x32_f16(a1, *(const half8*)&bR[sb + 64][0], accR, 0, 0, 0);
    accR = __builtin_amdgcn_mfma_f32_16x16x32_f16(a2, *(const half8*)&bR[sb + 128][0], accR, 0, 0, 0);
    accR = __builtin_amdgcn_mfma_f32_16x16x32_f16(a3, *(const half8*)&bR[sb + 192][0], accR, 0, 0, 0);
    accI = __builtin_amdgcn_mfma_f32_16x16x32_f16(a0, *(const half8*)&bI[sb][0], accI, 0, 0, 0);
    accI = __builtin_amdgcn_mfma_f32_16x16x32_f16(a1, *(const half8*)&bI[sb + 64][0], accI, 0, 0, 0);
    accI = __builtin_amdgcn_mfma_f32_16x16x32_f16(a2, *(const half8*)&bI[sb + 128][0], accI, 0, 0, 0);
    accI = __builtin_amdgcn_mfma_f32_16x16x32_f16(a3, *(const half8*)&bI[sb + 192][0], accI, 0, 0, 0);
    const int col = g * 16 + (lane & 15);
#pragma unroll
    for (int reg = 0; reg < 4; ++reg) {
      int r = base + rgrp + reg;
      if (r < n) {
        out[(size_t)r * 64 + col] = 0.5f * (accR[reg] + xrT[wave][rgrp + reg][col]);
        out[imag_off + (size_t)r * 64 + col] = 0.5f * accI[reg];
      }
    }
  }
}

extern "C" void kernel_launch(void* const* d_in, const int* in_sizes, int n_in,
                              void* d_out, int out_size, void* d_ws, size_t ws_size,
                              hipStream_t stream) {
  const float* x    = (const float*)d_in[0];
  const int*   ei   = (const int*)d_in[1];
  const float* ew   = (const float*)d_in[2];
  const float* Wr   = (const float*)d_in[3];
  const float* ln_g = (const float*)d_in[5];
  const float* ln_b = (const float*)d_in[6];
  const float* w1   = (const float*)d_in[7];
  const float* b1   = (const float*)d_in[8];
  const float* w2   = (const float*)d_in[9];
  const float* b2   = (const float*)d_in[10];
  const float* g1w  = (const float*)d_in[11];
  const float* g1b  = (const float*)d_in[12];
  const float* g2w  = (const float*)d_in[13];
  const float* g2b  = (const float*)d_in[14];
  const float* aw1  = (const float*)d_in[15];
  const float* ab1  = (const float*)d_in[16];
  const float* aw2  = (const float*)d_in[17];
  const float* ab2  = (const float*)d_in[18];
  const float* aw3  = (const float*)d_in[19];
  const float* ab3  = (const float*)d_in[20];
  const int n = in_sizes[0] / 64;
  const int e = in_sizes[1] / 2;
  float* out = (float*)d_out;

  float* ws = (float*)d_ws;
  float* Wg1  = ws;                           // 4096
  float* C0G1 = ws + 4096;                    // 64
  float* UrT  = ws + 4160;                    // 4096
  float* UiT  = ws + 8256;                    // 4096
  float* z2g  = ws + 12352;                   // 64
  float* pG   = ws + 12416;                   // 4096
  unsigned* AdjU = (unsigned*)(ws + 20544);   // 4096 u32 (zero region start)
  unsigned* cnt = AdjU + 4096;                // n
  unsigned* cur = cnt + n;                    // n
  unsigned* off = cur + n;                    // n+1 (fully written by scan)
  size_t p0 = (20544 + 4096 + 3 * (size_t)n + 1 + 63) & ~(size_t)63;
  int2* recSC = (int2*)(ws + p0);             // e int2
  size_t p2 = (p0 + 2 * (size_t)e + 63) & ~(size_t)63;
  ushort_t* R = (ushort_t*)(ws + p2);         // 64n f32-units
  size_t p3 = (p2 + 64 * (size_t)n + 63) & ~(size_t)63;
  float* AdP = ws + p3;                       // 64n f32-units
  size_t p4 = (p3 + 64 * (size_t)n + 63) & ~(size_t)63;
  __half* Crh = (__half*)(ws + p4);           // 32n
  size_t p5 = (p4 + 32 * (size_t)n + 63) & ~(size_t)63;
  __half* Srh = (__half*)(ws + p5);           // 32n

  const int ntiles = (n + 15) >> 4;
  const int nb = (ntiles + 3) >> 2;

  hipMemsetAsync(AdjU, 0, (4096 + 2 * (size_t)n) * 4, stream);
  kCountPrep<<<1025, 256, 0, stream>>>(ei, e, cnt, AdjU, ln_g, ln_b, w1, b1, Wg1, C0G1);
  kNodeMSG2<<<nb + 2, 256, 0, stream>>>(x, Wr, Wg1, C0G1, w2, b2, R, AdP, Crh, Srh, n, ntiles,
                                        nb, cnt, off, AdjU, g1w, g1b, g2w, g2b,
                                        aw1, ab1, aw2, ab2, z2g);
  kPhaseTanh<<<1040, 256, 0, stream>>>(ei, ew, e, R, AdP, C0G1, w2, b2, off, cur, recSC,
                                       z2g, aw3, ab3, pG);
  kScatterExpm<<<513, 1024, 0, stream>>>(off, recSC, R, Crh, Srh, n, pG, UrT, UiT);
  kFinalM<<<nb, 256, 0, stream>>>(x, Crh, Srh, UrT, UiT, out, n, ntiles);
}

// Round 22
// 265.103 us; speedup vs baseline: 1.2507x; 1.2457x over previous
//
#include <hip/hip_runtime.h>
#include <hip/hip_bf16.h>
#include <hip/hip_fp16.h>

#define MAXPH 0.78539816339744831f
typedef unsigned short ushort_t;
typedef _Float16 half8 __attribute__((ext_vector_type(8)));
typedef float f32x4 __attribute__((ext_vector_type(4)));

__device__ __forceinline__ float wsum64(float v) {
#pragma unroll
  for (int o = 32; o > 0; o >>= 1) v += __shfl_xor(v, o);
  return v;
}
__device__ __forceinline__ float bf2f(ushort_t u) {
  return __uint_as_float(((unsigned)u) << 16);
}

// ---- kCountPrep: blocks [0,1024) = per-dst histogram + AdjU; block 1024 = prep Wg1/C0G1
__global__ __launch_bounds__(256) void kCountPrep(
    const int* __restrict__ ei, int ne, unsigned* __restrict__ cnt,
    unsigned* __restrict__ AdjU,
    const float* __restrict__ ln_g, const float* __restrict__ ln_b,
    const float* __restrict__ w1, const float* __restrict__ b1,
    float* __restrict__ Wg1, float* __restrict__ C0G1) {
  if (blockIdx.x < 1024) {
    int t = blockIdx.x * 256 + threadIdx.x;
    int st = 1024 * 256;
    for (int e = t; e < ne; e += st) {
      int s = ei[e];
      int d = ei[ne + e];
      atomicAdd(&cnt[d], 1u);
      if ((unsigned)(s | d) < 64u) atomicAdd(&AdjU[d * 64 + s], 1u);
    }
  } else {
    int tt = threadIdx.x;
    for (int idx = tt; idx < 4096; idx += 256) {
      int j = idx >> 5;
      Wg1[idx] = ln_g[j] * w1[idx];
    }
    if (tt < 32) {
      float c0 = b1[tt], g1 = 0.f;
      for (int j = 0; j < 128; ++j) {
        float w = w1[j * 32 + tt];
        c0 = fmaf(ln_b[j], w, c0);
        g1 = fmaf(ln_g[j], w, g1);
      }
      C0G1[tt] = c0;
      C0G1[32 + tt] = g1;
    }
  }
}

// ---- kNodeMSG3: [0,nb) = MFMA node; [nb,nb+nscan) = decoupled-lookback scan; nb+nscan = GCN
__global__ __launch_bounds__(256) void kNodeMSG3(
    const float* __restrict__ x, const float* __restrict__ Wr,
    const float* __restrict__ Wg1, const float* __restrict__ C0G1,
    const float* __restrict__ w2, const float* __restrict__ b2,
    ushort_t* __restrict__ R, float* __restrict__ AdP,
    __half* __restrict__ Crh, __half* __restrict__ Srh, int n, int ntiles, int nb,
    int nscan, const unsigned* __restrict__ cnt, unsigned* __restrict__ off,
    unsigned* __restrict__ tick, unsigned long long* __restrict__ state,
    const unsigned* __restrict__ AdjU,
    const float* __restrict__ g1w, const float* __restrict__ g1b,
    const float* __restrict__ g2w, const float* __restrict__ g2b,
    const float* __restrict__ aw1, const float* __restrict__ ab1,
    const float* __restrict__ aw2, const float* __restrict__ ab2,
    float* __restrict__ z2g) {
  __shared__ float SHF[8832];  // 35328 B union
  const int tid = threadIdx.x;
  const int bid = blockIdx.x;

  if (bid >= nb && bid < nb + nscan) {
    // ======== decoupled-lookback exclusive scan, 1024 elems/tile ========
    unsigned* sh = (unsigned*)SHF;  // [0]=tile [1]=total [2]=base [4..7]=warpsum
    const int l = tid & 63, w = tid >> 6;
    if (tid == 0) sh[0] = atomicAdd(tick, 1u);
    __syncthreads();
    const unsigned tile = sh[0];
    const int i0 = (int)tile * 1024 + tid * 4;
    unsigned v0 = 0, v1 = 0, v2 = 0, v3 = 0;
    if (i0 + 4 <= n) {
      uint4 u4 = *(const uint4*)(cnt + i0);
      v0 = u4.x; v1 = u4.y; v2 = u4.z; v3 = u4.w;
    } else if (i0 < n) {
      v0 = cnt[i0];
      if (i0 + 1 < n) v1 = cnt[i0 + 1];
      if (i0 + 2 < n) v2 = cnt[i0 + 2];
      if (i0 + 3 < n) v3 = cnt[i0 + 3];
    }
    unsigned tsum = v0 + v1 + v2 + v3;
    unsigned inc = tsum;
#pragma unroll
    for (int o = 1; o < 64; o <<= 1) {
      unsigned u = __shfl_up(inc, o);
      if (l >= o) inc += u;
    }
    if (l == 63) sh[4 + w] = inc;
    __syncthreads();
    if (tid == 0) {
      unsigned a = 0;
      for (int i = 0; i < 4; ++i) {
        unsigned c = sh[4 + i];
        sh[4 + i] = a;
        a += c;
      }
      sh[1] = a;
    }
    __syncthreads();
    const unsigned texc = sh[4 + w] + inc - tsum;
    if (tid == 0) {
      const unsigned total = sh[1];
      unsigned run = 0;
      if (tile == 0) {
        __hip_atomic_store(&state[0], (2ULL << 32) | (unsigned long long)total,
                           __ATOMIC_RELEASE, __HIP_MEMORY_SCOPE_AGENT);
      } else {
        __hip_atomic_store(&state[tile], (1ULL << 32) | (unsigned long long)total,
                           __ATOMIC_RELEASE, __HIP_MEMORY_SCOPE_AGENT);
        int t2 = (int)tile - 1;
        while (t2 >= 0) {
          unsigned long long sv;
          do {
            sv = __hip_atomic_load(&state[t2], __ATOMIC_ACQUIRE, __HIP_MEMORY_SCOPE_AGENT);
          } while ((sv >> 32) == 0ULL);
          run += (unsigned)sv;
          if ((sv >> 32) == 2ULL) break;
          --t2;
        }
        __hip_atomic_store(&state[tile], (2ULL << 32) | (unsigned long long)(run + total),
                           __ATOMIC_RELEASE, __HIP_MEMORY_SCOPE_AGENT);
      }
      sh[2] = run;
      if (tile == (unsigned)(nscan - 1)) off[n] = run + total;
    }
    __syncthreads();
    unsigned run2 = sh[2] + texc;
    if (i0 < n) {
      off[i0] = run2;
      run2 += v0;
      if (i0 + 1 < n) {
        off[i0 + 1] = run2;
        run2 += v1;
        if (i0 + 2 < n) {
          off[i0 + 2] = run2;
          run2 += v2;
          if (i0 + 3 < n) off[i0 + 3] = run2;
        }
      }
    }
    return;
  }
  if (bid == nb + nscan) {
    // ======== GCN x2 + pool + MLP -> z2 (256 threads, parallel reductions) ========
    float* L0 = SHF;
    float* L1 = SHF + 4160;
    float* sdv = SHF + 8320;
    float* sts = sdv + 64;
    float* sgp = sts + 64;
    float* sz1 = sgp + 64;
    float* part = sz1 + 64;
    const int kk6 = tid & 63, mq = tid >> 6;
    for (int idx = tid; idx < 4096; idx += 256) {
      int r = idx >> 6, c = idx & 63;
      L0[r * 65 + c] = (float)AdjU[idx];
    }
    __syncthreads();
    {
      float p = 0.f;
      for (int c = mq * 16; c < mq * 16 + 16; ++c) p += L0[kk6 * 65 + c];
      part[mq * 64 + kk6] = p;
    }
    __syncthreads();
    if (tid < 64)
      sdv[tid] = rsqrtf(1.f + part[tid] + part[64 + tid] + part[128 + tid] + part[192 + tid]);
    __syncthreads();
    {
      float p = 0.f;
      for (int c = mq * 16; c < mq * 16 + 16; ++c) p += L0[kk6 * 65 + c] * sdv[c];
      part[mq * 64 + kk6] = p;
    }
    __syncthreads();
    if (tid < 64) sts[tid] = part[tid] + part[64 + tid] + part[128 + tid] + part[192 + tid];
    __syncthreads();
    for (int idx = tid; idx < 4096; idx += 256) {
      int d = idx >> 6, c = idx & 63;
      L1[d * 65 + c] = fmaxf(fmaf(g1w[c], fmaf(sts[d], sdv[d], sdv[d] * sdv[d]), g1b[c]), 0.f);
    }
    __syncthreads();
    const int i2 = tid >> 2, j0 = (tid & 3) << 4;
    float xw[16];
#pragma unroll
    for (int q = 0; q < 16; ++q) xw[q] = 0.f;
    for (int m = 0; m < 64; ++m) {
      float hm = L1[i2 * 65 + m];
      const float* wp = g2w + m * 64 + j0;
#pragma unroll
      for (int q = 0; q < 16; ++q) xw[q] = fmaf(hm, wp[q], xw[q]);
    }
    __syncthreads();
#pragma unroll
    for (int q = 0; q < 16; ++q) L1[i2 * 65 + j0 + q] = xw[q];
    __syncthreads();
    float a[16];
#pragma unroll
    for (int q = 0; q < 16; ++q) a[q] = 0.f;
    for (int s2 = 0; s2 < 64; ++s2) {
      float wv = L0[i2 * 65 + s2] * sdv[s2];
#pragma unroll
      for (int q = 0; q < 16; ++q) a[q] = fmaf(wv, L1[s2 * 65 + j0 + q], a[q]);
    }
    float di = sdv[i2], sc = di * di;
    float h2v[16];
#pragma unroll
    for (int q = 0; q < 16; ++q)
      h2v[q] = fmaf(a[q], di, fmaf(sc, L1[i2 * 65 + j0 + q], g2b[j0 + q]));
    __syncthreads();
#pragma unroll
    for (int q = 0; q < 16; ++q) L1[i2 * 65 + j0 + q] = h2v[q];
    __syncthreads();
    {
      float p = 0.f;
      for (int r = mq * 16; r < mq * 16 + 16; ++r) p += L1[r * 65 + kk6];
      part[mq * 64 + kk6] = p;
    }
    __syncthreads();
    if (tid < 64)
      sgp[tid] = (part[tid] + part[64 + tid] + part[128 + tid] + part[192 + tid]) * 0.015625f;
    __syncthreads();
    {
      float p = 0.f;
      for (int m = mq * 16; m < mq * 16 + 16; ++m) p = fmaf(sgp[m], aw1[m * 64 + kk6], p);
      part[mq * 64 + kk6] = p;
    }
    __syncthreads();
    if (tid < 64)
      sz1[tid] = fmaxf(ab1[tid] + part[tid] + part[64 + tid] + part[128 + tid] + part[192 + tid], 0.f);
    __syncthreads();
    {
      float p = 0.f;
      for (int m = mq * 16; m < mq * 16 + 16; ++m) p = fmaf(sz1[m], aw2[m * 64 + kk6], p);
      part[mq * 64 + kk6] = p;
    }
    __syncthreads();
    if (tid < 64)
      z2g[tid] = fmaxf(ab2[tid] + part[tid] + part[64 + tid] + part[128 + tid] + part[192 + tid], 0.f);
    return;
  }

  // ======== node MFMA path ========
  _Float16* bWr = (_Float16*)SHF;
  _Float16* bAd = (_Float16*)(SHF + 2048);
  _Float16* bAs = (_Float16*)(SHF + 3072);
  _Float16* cmT = (_Float16*)(SHF + 4096);
  const int lane = tid & 63;
  const int wave = tid >> 6;
  for (int slot = tid; slot < 512; slot += 256) {
    int g = slot >> 7;
    int c = (slot >> 6) & 1;
    int l = slot & 63;
    int col = g * 16 + (l & 15);
    int kb0 = c * 32 + ((l >> 4) << 3);
#pragma unroll
    for (int j = 0; j < 8; ++j) bWr[slot * 8 + j] = (_Float16)Wr[(kb0 + j) * 64 + col];
  }
  {
    int slot = tid;
    int g2 = slot >> 7;
    int c = (slot >> 6) & 1;
    int l = slot & 63;
    int col = g2 * 16 + (l & 15);
    int kb0 = c * 32 + ((l >> 4) << 3);
#pragma unroll
    for (int j = 0; j < 8; ++j) {
      bAd[slot * 8 + j] = (_Float16)Wg1[(kb0 + j) * 32 + col];
      bAs[slot * 8 + j] = (_Float16)Wg1[(64 + kb0 + j) * 32 + col];
    }
  }
  __syncthreads();
  const int tile = bid * 4 + wave;
  if (tile >= ntiles) return;
  const int base = tile << 4;
  const int row = lane & 15;
  const int kb = (lane >> 4) << 3;
  const int nodeA = min(base + row, n - 1);
  const float* xp = x + (size_t)nodeA * 64;
  float xv[8], xh[8];
  *(float4*)&xv[0] = *(const float4*)(xp + kb);
  *(float4*)&xv[4] = *(const float4*)(xp + kb + 4);
  *(float4*)&xh[0] = *(const float4*)(xp + 32 + kb);
  *(float4*)&xh[4] = *(const float4*)(xp + 32 + kb + 4);
  float s1 = 0.f, s2 = 0.f;
#pragma unroll
  for (int j = 0; j < 8; ++j) {
    s1 += xv[j] + xh[j];
    s2 += xv[j] * xv[j] + xh[j] * xh[j];
  }
  s1 += __shfl_xor(s1, 16);
  s1 += __shfl_xor(s1, 32);
  s2 += __shfl_xor(s2, 16);
  s2 += __shfl_xor(s2, 32);
  float mean = s1 * 0.015625f;
  float var = fmaf(-mean, mean, s2 * 0.015625f);
  float rstd = rsqrtf(var + 1e-5f);
  half8 aLo, aHi;
#pragma unroll
  for (int j = 0; j < 8; ++j) {
    aLo[j] = (_Float16)((xv[j] - mean) * rstd);
    aHi[j] = (_Float16)((xh[j] - mean) * rstd);
  }
  f32x4 accH[4];
#pragma unroll
  for (int g = 0; g < 4; ++g) {
    f32x4 z4 = {0.f, 0.f, 0.f, 0.f};
    z4 = __builtin_amdgcn_mfma_f32_16x16x32_f16(aLo, *(const half8*)&bWr[(g * 128 + lane) * 8], z4, 0, 0, 0);
    z4 = __builtin_amdgcn_mfma_f32_16x16x32_f16(aHi, *(const half8*)&bWr[(g * 128 + 64 + lane) * 8], z4, 0, 0, 0);
    accH[g] = z4;
  }
  float cm[4][4];
  float p1[4] = {0.f, 0.f, 0.f, 0.f}, p2[4] = {0.f, 0.f, 0.f, 0.f};
#pragma unroll
  for (int g = 0; g < 4; ++g)
#pragma unroll
    for (int r = 0; r < 4; ++r) {
      float hv = accH[g][r];
      float m = fminf(sqrtf(fmaf(hv, hv, 1e-8f)), 10.f);
      cm[g][r] = m;
      p1[r] += m;
      p2[r] += m * m;
    }
#pragma unroll
  for (int o = 1; o <= 8; o <<= 1)
#pragma unroll
    for (int r = 0; r < 4; ++r) {
      p1[r] += __shfl_xor(p1[r], o);
      p2[r] += __shfl_xor(p2[r], o);
    }
  const int rgrp = (lane >> 4) << 2;
#pragma unroll
  for (int g = 0; g < 4; ++g)
#pragma unroll
    for (int r = 0; r < 4; ++r)
      cmT[((wave * 16) + rgrp + r) * 72 + g * 16 + (lane & 15)] = (_Float16)cm[g][r];
  half8 cLo = *(const half8*)&cmT[((wave * 16) + row) * 72 + kb];
  half8 cHi = *(const half8*)&cmT[((wave * 16) + row) * 72 + 32 + kb];
  f32x4 accAd[2], accAs[2];
#pragma unroll
  for (int g2 = 0; g2 < 2; ++g2) {
    f32x4 z4 = {0.f, 0.f, 0.f, 0.f};
    z4 = __builtin_amdgcn_mfma_f32_16x16x32_f16(cLo, *(const half8*)&bAd[(g2 * 128 + lane) * 8], z4, 0, 0, 0);
    z4 = __builtin_amdgcn_mfma_f32_16x16x32_f16(cHi, *(const half8*)&bAd[(g2 * 128 + 64 + lane) * 8], z4, 0, 0, 0);
    accAd[g2] = z4;
    f32x4 w4 = {0.f, 0.f, 0.f, 0.f};
    w4 = __builtin_amdgcn_mfma_f32_16x16x32_f16(cLo, *(const half8*)&bAs[(g2 * 128 + lane) * 8], w4, 0, 0, 0);
    w4 = __builtin_amdgcn_mfma_f32_16x16x32_f16(cHi, *(const half8*)&bAs[(g2 * 128 + 64 + lane) * 8], w4, 0, 0, 0);
    accAs[g2] = w4;
  }
  const float b2r = b2[0];
  float c0v[2], g1v[2], w2v[2];
#pragma unroll
  for (int g2 = 0; g2 < 2; ++g2) {
    int k = g2 * 16 + (lane & 15);
    c0v[g2] = C0G1[k];
    g1v[g2] = C0G1[32 + k];
    w2v[g2] = w2[k];
  }
  float zp[4];
#pragma unroll
  for (int r = 0; r < 4; ++r) {
    float meanE = p1[r] * 0.015625f;
    float varE = fmaf(-meanE, meanE, p2[r] * 0.015625f);
    float rstdE = rsqrtf(varE + 1e-5f);
    float zz = 0.f;
#pragma unroll
    for (int g2 = 0; g2 < 2; ++g2) {
      float pre = fmaf(rstdE, fmaf(-meanE, g1v[g2], accAd[g2][r] + accAs[g2][r]), c0v[g2]);
      zz = fmaf(fmaxf(pre, 0.f), w2v[g2], zz);
    }
    zp[r] = zz;
  }
#pragma unroll
  for (int o = 1; o <= 8; o <<= 1)
#pragma unroll
    for (int r = 0; r < 4; ++r) zp[r] += __shfl_xor(zp[r], o);
  float csv[4], snv[4];
#pragma unroll
  for (int r = 0; r < 4; ++r) {
    float coup = 1.f / (1.f + expf(-(zp[r] + b2r)));
    float ph = fminf(0.3f * coup, MAXPH);
    sincosf(ph, &snv[r], &csv[r]);
  }
  const int colb = lane & 15;
#pragma unroll
  for (int r = 0; r < 4; ++r) {
    int node = base + rgrp + r;
    if (node >= n) break;
#pragma unroll
    for (int g = 0; g < 4; ++g) {
      int col = g * 16 + colb;
      float hv = accH[g][r];
      __hip_bfloat16 hb = __float2bfloat16(hv);
      R[(size_t)node * 128 + col] = *(ushort_t*)&hb;
      Crh[(size_t)node * 64 + col] = __float2half(hv * csv[r]);
      Srh[(size_t)node * 64 + col] = __float2half(hv * snv[r]);
    }
    ushort_t* ap = (ushort_t*)(AdP + (size_t)node * 64);
#pragma unroll
    for (int g2 = 0; g2 < 2; ++g2) {
      int col = g2 * 16 + colb;
      __hip_bfloat16 ab = __float2bfloat16(accAd[g2][r]);
      ap[col] = *(ushort_t*)&ab;
      __hip_bfloat16 sb2 = __float2bfloat16(accAs[g2][r]);
      R[(size_t)node * 128 + 64 + col] = *(ushort_t*)&sb2;
    }
    if (colb == 0) {
      float* sp = (float*)(R + (size_t)node * 128 + 96);
      sp[0] = p1[r];
      sp[1] = p2[r];
      float* dp = AdP + (size_t)node * 64;
      dp[16] = p1[r];
      dp[17] = p2[r];
    }
  }
}

// ---- kPhaseTanh: blocks [0,1024) = lane-per-edge phase -> recs; [1024,1040) = tanh
__global__ __launch_bounds__(256) void kPhaseTanh(
    const int* __restrict__ ei, const float* __restrict__ ew, int ne,
    const ushort_t* __restrict__ R, const float* __restrict__ AdP,
    const float* __restrict__ C0G1, const float* __restrict__ w2,
    const float* __restrict__ b2,
    const unsigned* __restrict__ off, unsigned* __restrict__ cur,
    int2* __restrict__ recSC,
    const float* __restrict__ z2g, const float* __restrict__ aw3,
    const float* __restrict__ ab3, float* __restrict__ pG) {
  if (blockIdx.x >= 1024) {
    int rc = (blockIdx.x - 1024) * 256 + threadIdx.x;
    float a = ab3[rc];
    for (int m = 0; m < 64; ++m) a = fmaf(z2g[m], aw3[m * 4096 + rc], a);
    pG[rc] = tanhf(a);
    return;
  }
  const float b2r = b2[0];
  int t = blockIdx.x * 256 + threadIdx.x;
  int st = 1024 * 256;
  for (int e = t; e < ne; e += st) {
    int s = ei[e];
    int d = ei[ne + e];
    const ushort_t* rs = R + (size_t)s * 128;
    const float* bp = AdP + (size_t)d * 64;
    float2 ps = *(const float2*)(rs + 96);
    float2 pd = *(const float2*)(bp + 16);
    float meanE = (ps.x + pd.x) * 0.0078125f;
    float varE = fmaf(-meanE, meanE, (ps.y + pd.y) * 0.0078125f);
    float rstdE = rsqrtf(varE + 1e-5f);
    const uint4* asq = (const uint4*)(rs + 64);
    const uint4* adq = (const uint4*)bp;
    float z = b2r;
#pragma unroll
    for (int q = 0; q < 4; ++q) {
      uint4 ua = adq[q];
      uint4 ub = asq[q];
      unsigned av[4] = {ua.x, ua.y, ua.z, ua.w};
      unsigned bv[4] = {ub.x, ub.y, ub.z, ub.w};
#pragma unroll
      for (int p = 0; p < 4; ++p) {
        int k0 = q * 8 + p * 2;
        float a0 = __uint_as_float(av[p] << 16);
        float a1 = __uint_as_float(av[p] & 0xFFFF0000u);
        float b0 = __uint_as_float(bv[p] << 16);
        float b1 = __uint_as_float(bv[p] & 0xFFFF0000u);
        float pre0 = fmaf(rstdE, fmaf(-meanE, C0G1[32 + k0], a0 + b0), C0G1[k0]);
        float pre1 = fmaf(rstdE, fmaf(-meanE, C0G1[32 + k0 + 1], a1 + b1), C0G1[k0 + 1]);
        z = fmaf(fmaxf(pre0, 0.f), w2[k0], z);
        z = fmaf(fmaxf(pre1, 0.f), w2[k0 + 1], z);
      }
    }
    float coup = 1.f / (1.f + expf(-z));
    float cw = fminf(fmaxf(ew[e], 0.1f), 2.f);
    float ph = fminf(0.3f * coup * cw, MAXPH);
    float sn, cs;
    sincosf(ph, &sn, &cs);
    unsigned p = atomicAdd(&cur[d], 1u);
    unsigned pos = off[d] + p;
    __half2 h2 = __floats2half2_rn(cs, sn);
    int2 rec;
    rec.x = s;
    rec.y = *(int*)&h2;
    recSC[pos] = rec;
  }
}

// ---- kScatterExpm: blocks [0,G-1) = wave-per-node gather; block G-1 = expm
__global__ __launch_bounds__(1024) void kScatterExpm(
    const unsigned* __restrict__ off, const int2* __restrict__ recSC,
    const ushort_t* __restrict__ R,
    __half* __restrict__ Crh, __half* __restrict__ Srh, int n,
    const float* __restrict__ pG, float* __restrict__ UrT, float* __restrict__ UiT) {
  __shared__ float Br[64 * 65], Bi[64 * 65];
  __shared__ float Xr[64 * 68], Xi[64 * 68];
  __shared__ float rowsum[64];
  __shared__ int sSh;
  const int tid = threadIdx.x;
  if (blockIdx.x == gridDim.x - 1) {
    const float SC0 = 0.05f;  // 0.1 * 0.5
    for (int idx = tid; idx < 4096; idx += 1024) {
      int r = idx >> 6, c = idx & 63;
      float pr = pG[r * 64 + c], pt = pG[c * 64 + r];
      Br[r * 65 + c] = (pr - pt) * SC0;
      Bi[r * 65 + c] = (pr + pt) * SC0;
    }
    __syncthreads();
    if (tid < 64) {
      float a = 0.f;
      for (int c = 0; c < 64; ++c) a += fabsf(Br[tid * 65 + c]) + fabsf(Bi[tid * 65 + c]);
      rowsum[tid] = a;
    }
    __syncthreads();
    if (tid == 0) {
      float m = 0.f;
      for (int i2 = 0; i2 < 64; ++i2) m = fmaxf(m, rowsum[i2]);
      int s = 0;
      while (m > 0.25f && s < 16) {
        m *= 0.5f;
        ++s;
      }
      sSh = s;
    }
    __syncthreads();
    const int sVal = sSh;
    const float scale = ldexpf(1.f, -sVal);
    for (int idx = tid; idx < 4096; idx += 1024) {
      int r = idx >> 6, c = idx & 63;
      float br = Br[r * 65 + c] * scale;
      float bi = Bi[r * 65 + c] * scale;
      Br[r * 65 + c] = br;
      Bi[r * 65 + c] = bi;
      Xr[r * 68 + c] = (r == c ? 1.f : 0.f) + br * (1.f / 6.f);
      Xi[r * 68 + c] = bi * (1.f / 6.f);
    }
    __syncthreads();
    const int i = tid >> 4, j0 = (tid & 15) << 2;
    for (int kk = 5; kk >= 1; --kk) {
      float ar[4] = {0, 0, 0, 0}, ai[4] = {0, 0, 0, 0};
      for (int m = 0; m < 64; ++m) {
        float br = Br[i * 65 + m], bi = Bi[i * 65 + m];
        float4 xr4 = *(const float4*)&Xr[m * 68 + j0];
        float4 xi4 = *(const float4*)&Xi[m * 68 + j0];
        float xr[4] = {xr4.x, xr4.y, xr4.z, xr4.w};
        float xi[4] = {xi4.x, xi4.y, xi4.z, xi4.w};
#pragma unroll
        for (int q = 0; q < 4; ++q) {
          ar[q] = fmaf(br, xr[q], fmaf(-bi, xi[q], ar[q]));
          ai[q] = fmaf(br, xi[q], fmaf(bi, xr[q], ai[q]));
        }
      }
      __syncthreads();
      float inv = 1.f / (float)kk;
#pragma unroll
      for (int q = 0; q < 4; ++q) {
        int c = j0 + q;
        Xr[i * 68 + c] = (i == c ? 1.f : 0.f) + ar[q] * inv;
        Xi[i * 68 + c] = ai[q] * inv;
      }
      __syncthreads();
    }
    for (int sq = 0; sq < sVal; ++sq) {
      float ar[4] = {0, 0, 0, 0}, ai[4] = {0, 0, 0, 0};
      for (int m = 0; m < 64; ++m) {
        float br = Xr[i * 68 + m], bi = Xi[i * 68 + m];
        float4 xr4 = *(const float4*)&Xr[m * 68 + j0];
        float4 xi4 = *(const float4*)&Xi[m * 68 + j0];
        float xr[4] = {xr4.x, xr4.y, xr4.z, xr4.w};
        float xi[4] = {xi4.x, xi4.y, xi4.z, xi4.w};
#pragma unroll
        for (int q = 0; q < 4; ++q) {
          ar[q] = fmaf(br, xr[q], fmaf(-bi, xi[q], ar[q]));
          ai[q] = fmaf(br, xi[q], fmaf(bi, xr[q], ai[q]));
        }
      }
      __syncthreads();
#pragma unroll
      for (int q = 0; q < 4; ++q) {
        Xr[i * 68 + j0 + q] = ar[q];
        Xi[i * 68 + j0 + q] = ai[q];
      }
      __syncthreads();
    }
    for (int idx = tid; idx < 4096; idx += 1024) {
      int a2 = idx >> 6, b2i = idx & 63;
      UrT[idx] = Xr[b2i * 68 + a2];
      UiT[idx] = Xi[b2i * 68 + a2];
    }
    return;
  }
  const int lane = tid & 63;
  const int wid = (blockIdx.x * 1024 + tid) >> 6;
  const int nw = ((gridDim.x - 1) * 1024) >> 6;
  for (int d = wid; d < n; d += nw) {
    unsigned u0 = off[d], u1 = off[d + 1];
    float accR = 0.f, accI = 0.f;
    unsigned j = u0;
    for (; j + 8 <= u1; j += 8) {
      int s8[8];
      float2 c8[8];
#pragma unroll
      for (int k = 0; k < 8; ++k) {
        int2 rec = recSC[j + k];
        s8[k] = rec.x;
        __half2 h2 = *(__half2*)&rec.y;
        c8[k] = __half22float2(h2);
      }
#pragma unroll
      for (int k = 0; k < 8; ++k) {
        float hv = bf2f(R[(size_t)s8[k] * 128 + lane]);
        accR = fmaf(hv, c8[k].x, accR);
        accI = fmaf(hv, c8[k].y, accI);
      }
    }
    for (; j < u1; ++j) {
      int2 rec = recSC[j];
      __half2 h2 = *(__half2*)&rec.y;
      float2 c = __half22float2(h2);
      float hv = bf2f(R[(size_t)rec.x * 128 + lane]);
      accR = fmaf(hv, c.x, accR);
      accI = fmaf(hv, c.y, accI);
    }
    size_t idx = (size_t)d * 64 + lane;
    Crh[idx] = __float2half(__half2float(Crh[idx]) + accR);
    Srh[idx] = __float2half(__half2float(Srh[idx]) + accI);
  }
}

// ---- kFinalM: MFMA GEMM — OutR=[Cr|Sr]@[UrT;-UiT], OutI=[Cr|Sr]@[UiT;UrT]; +0.5*LN(x)
__global__ __launch_bounds__(256) void kFinalM(
    const float* __restrict__ x, const __half* __restrict__ Crh,
    const __half* __restrict__ Srh, const float* __restrict__ UrT,
    const float* __restrict__ UiT, float* __restrict__ out, int n, int ntiles) {
  __shared__ _Float16 bR[1024][8];
  __shared__ _Float16 bI[1024][8];
  __shared__ float xrT[4][16][65];
  const int tid = threadIdx.x;
  const int lane = tid & 63;
  const int wave = tid >> 6;
  for (int slot = tid; slot < 1024; slot += 256) {
    int g = slot >> 8;
    int c = (slot >> 6) & 3;
    int l = slot & 63;
    int col = g * 16 + (l & 15);
    int kb = c * 32 + ((l >> 4) << 3);
#pragma unroll
    for (int j = 0; j < 8; ++j) {
      int k = kb + j;
      float vr, vi;
      if (k < 64) {
        vr = UrT[k * 64 + col];
        vi = UiT[k * 64 + col];
      } else {
        vr = -UiT[(k - 64) * 64 + col];
        vi = UrT[(k - 64) * 64 + col];
      }
      bR[slot][j] = (_Float16)vr;
      bI[slot][j] = (_Float16)vi;
    }
  }
  __syncthreads();
  const int tile = blockIdx.x * 4 + wave;
  if (tile >= ntiles) return;
  const int base = tile << 4;
  for (int nn = 0; nn < 16; ++nn) {
    int node = min(base + nn, n - 1);
    float xv = x[(size_t)node * 64 + lane];
    float s1 = wsum64(xv);
    float s2 = wsum64(xv * xv);
    float mean = s1 * 0.015625f;
    float var = fmaf(-mean, mean, s2 * 0.015625f);
    xrT[wave][nn][lane] = (xv - mean) * rsqrtf(var + 1e-5f);
  }
  const int row = lane & 15;
  const int node = min(base + row, n - 1);
  const int kb = (lane >> 4) << 3;
  const _Float16* crp = (const _Float16*)(Crh + (size_t)node * 64);
  const _Float16* srp = (const _Float16*)(Srh + (size_t)node * 64);
  half8 a0 = *(const half8*)(crp + kb);
  half8 a1 = *(const half8*)(crp + 32 + kb);
  half8 a2 = *(const half8*)(srp + kb);
  half8 a3 = *(const half8*)(srp + 32 + kb);
  const size_t imag_off = (size_t)n * 64;
  const int rgrp = (lane >> 4) << 2;
#pragma unroll
  for (int g = 0; g < 4; ++g) {
    f32x4 accR = {0.f, 0.f, 0.f, 0.f};
    f32x4 accI = {0.f, 0.f, 0.f, 0.f};
    const int sb = g * 256 + lane;
    accR = __builtin_amdgcn_mfma_f32_16x16x32_f16(a0, *(const half8*)&bR[sb][0], accR, 0, 0, 0);
    accR = __builtin_amdgcn_mfma_f32_16x16x32_f16(a1, *(const half8*)&bR[sb + 64][0], accR, 0, 0, 0);
    accR = __builtin_amdgcn_mfma_f32_16x16x32_f16(a2, *(const half8*)&bR[sb + 128][0], accR, 0, 0, 0);
    accR = __builtin_amdgcn_mfma_f32_16x16x32_f16(a3, *(const half8*)&bR[sb + 192][0], accR, 0, 0, 0);
    accI = __builtin_amdgcn_mfma_f32_16x16x32_f16(a0, *(const half8*)&bI[sb][0], accI, 0, 0, 0);
    accI = __builtin_amdgcn_mfma_f32_16x16x32_f16(a1, *(const half8*)&bI[sb + 64][0], accI, 0, 0, 0);
    accI = __builtin_amdgcn_mfma_f32_16x16x32_f16(a2, *(const half8*)&bI[sb + 128][0], accI, 0, 0, 0);
    accI = __builtin_amdgcn_mfma_f32_16x16x32_f16(a3, *(const half8*)&bI[sb + 192][0], accI, 0, 0, 0);
    const int col = g * 16 + (lane & 15);
#pragma unroll
    for (int reg = 0; reg < 4; ++reg) {
      int r = base + rgrp + reg;
      if (r < n) {
        out[(size_t)r * 64 + col] = 0.5f * (accR[reg] + xrT[wave][rgrp + reg][col]);
        out[imag_off + (size_t)r * 64 + col] = 0.5f * accI[reg];
      }
    }
  }
}

extern "C" void kernel_launch(void* const* d_in, const int* in_sizes, int n_in,
                              void* d_out, int out_size, void* d_ws, size_t ws_size,
                              hipStream_t stream) {
  const float* x    = (const float*)d_in[0];
  const int*   ei   = (const int*)d_in[1];
  const float* ew   = (const float*)d_in[2];
  const float* Wr   = (const float*)d_in[3];
  const float* ln_g = (const float*)d_in[5];
  const float* ln_b = (const float*)d_in[6];
  const float* w1   = (const float*)d_in[7];
  const float* b1   = (const float*)d_in[8];
  const float* w2   = (const float*)d_in[9];
  const float* b2   = (const float*)d_in[10];
  const float* g1w  = (const float*)d_in[11];
  const float* g1b  = (const float*)d_in[12];
  const float* g2w  = (const float*)d_in[13];
  const float* g2b  = (const float*)d_in[14];
  const float* aw1  = (const float*)d_in[15];
  const float* ab1  = (const float*)d_in[16];
  const float* aw2  = (const float*)d_in[17];
  const float* ab2  = (const float*)d_in[18];
  const float* aw3  = (const float*)d_in[19];
  const float* ab3  = (const float*)d_in[20];
  const int n = in_sizes[0] / 64;
  const int e = in_sizes[1] / 2;
  float* out = (float*)d_out;

  const int nscan = (n + 1023) >> 10;

  float* ws = (float*)d_ws;
  float* Wg1  = ws;                           // 4096
  float* C0G1 = ws + 4096;                    // 64
  float* UrT  = ws + 4160;                    // 4096
  float* UiT  = ws + 8256;                    // 4096
  float* z2g  = ws + 12352;                   // 64
  float* pG   = ws + 12416;                   // 4096
  unsigned* AdjU = (unsigned*)(ws + 20544);   // 4096 u32 — zero region start
  unsigned* cnt = AdjU + 4096;                // n
  unsigned* cur = cnt + n;                    // n
  unsigned long long* state = (unsigned long long*)(cur + n);  // nscan u64 (8B-aligned)
  unsigned* tick = (unsigned*)(state + nscan);                 // 2 u32 (tick + pad)
  unsigned* off = tick + 2;                   // n+1 (fully written by scan)
  size_t zeroEndF = 20544 + 4096 + 2 * (size_t)n + 2 * (size_t)nscan + 2;
  size_t p0 = (zeroEndF + (size_t)n + 1 + 63) & ~(size_t)63;
  int2* recSC = (int2*)(ws + p0);             // e int2
  size_t p2 = (p0 + 2 * (size_t)e + 63) & ~(size_t)63;
  ushort_t* R = (ushort_t*)(ws + p2);         // 64n f32-units
  size_t p3 = (p2 + 64 * (size_t)n + 63) & ~(size_t)63;
  float* AdP = ws + p3;                       // 64n f32-units
  size_t p4 = (p3 + 64 * (size_t)n + 63) & ~(size_t)63;
  __half* Crh = (__half*)(ws + p4);           // 32n
  size_t p5 = (p4 + 32 * (size_t)n + 63) & ~(size_t)63;
  __half* Srh = (__half*)(ws + p5);           // 32n

  const int ntiles = (n + 15) >> 4;
  const int nb = (ntiles + 3) >> 2;

  hipMemsetAsync(AdjU, 0, (4096 + 2 * (size_t)n + 2 * (size_t)nscan + 2) * 4, stream);
  kCountPrep<<<1025, 256, 0, stream>>>(ei, e, cnt, AdjU, ln_g, ln_b, w1, b1, Wg1, C0G1);
  kNodeMSG3<<<nb + nscan + 1, 256, 0, stream>>>(
      x, Wr, Wg1, C0G1, w2, b2, R, AdP, Crh, Srh, n, ntiles, nb, nscan, cnt, off,
      tick, state, AdjU, g1w, g1b, g2w, g2b, aw1, ab1, aw2, ab2, z2g);
  kPhaseTanh<<<1040, 256, 0, stream>>>(ei, ew, e, R, AdP, C0G1, w2, b2, off, cur, recSC,
                                       z2g, aw3, ab3, pG);
  kScatterExpm<<<513, 1024, 0, stream>>>(off, recSC, R, Crh, Srh, n, pG, UrT, UiT);
  kFinalM<<<nb, 256, 0, stream>>>(x, Crh, Srh, UrT, UiT, out, n, ntiles);
}

// Round 23
// 262.320 us; speedup vs baseline: 1.2640x; 1.0106x over previous
//
#include <hip/hip_runtime.h>
#include <hip/hip_bf16.h>
#include <hip/hip_fp16.h>

#define MAXPH 0.78539816339744831f
typedef unsigned short ushort_t;
typedef _Float16 half8 __attribute__((ext_vector_type(8)));
typedef float f32x4 __attribute__((ext_vector_type(4)));

__device__ __forceinline__ float wsum64(float v) {
#pragma unroll
  for (int o = 32; o > 0; o >>= 1) v += __shfl_xor(v, o);
  return v;
}
__device__ __forceinline__ float bf2f(ushort_t u) {
  return __uint_as_float(((unsigned)u) << 16);
}

// ---- kCountPrep: blocks [0,1024) = per-dst histogram + AdjU; block 1024 = prep Wg1/C0G1
__global__ __launch_bounds__(256) void kCountPrep(
    const int* __restrict__ ei, int ne, unsigned* __restrict__ cnt,
    unsigned* __restrict__ AdjU,
    const float* __restrict__ ln_g, const float* __restrict__ ln_b,
    const float* __restrict__ w1, const float* __restrict__ b1,
    float* __restrict__ Wg1, float* __restrict__ C0G1) {
  if (blockIdx.x < 1024) {
    int t = blockIdx.x * 256 + threadIdx.x;
    int st = 1024 * 256;
    for (int e = t; e < ne; e += st) {
      int s = ei[e];
      int d = ei[ne + e];
      atomicAdd(&cnt[d], 1u);
      if ((unsigned)(s | d) < 64u) atomicAdd(&AdjU[d * 64 + s], 1u);
    }
  } else {
    int tt = threadIdx.x;
    for (int idx = tt; idx < 4096; idx += 256) {
      int j = idx >> 5;
      Wg1[idx] = ln_g[j] * w1[idx];
    }
    if (tt < 32) {
      float c0 = b1[tt], g1 = 0.f;
      for (int j = 0; j < 128; ++j) {
        float w = w1[j * 32 + tt];
        c0 = fmaf(ln_b[j], w, c0);
        g1 = fmaf(ln_g[j], w, g1);
      }
      C0G1[tt] = c0;
      C0G1[32 + tt] = g1;
    }
  }
}

// ---- kNodeMSG3: [0,nb) = MFMA node; [nb,nb+nscan) = decoupled-lookback scan; nb+nscan = GCN
__global__ __launch_bounds__(256) void kNodeMSG3(
    const float* __restrict__ x, const float* __restrict__ Wr,
    const float* __restrict__ Wg1, const float* __restrict__ C0G1,
    const float* __restrict__ w2, const float* __restrict__ b2,
    ushort_t* __restrict__ R, float* __restrict__ AdP,
    __half* __restrict__ Crh, __half* __restrict__ Srh, int n, int ntiles, int nb,
    int nscan, const unsigned* __restrict__ cnt, unsigned* __restrict__ off,
    unsigned* __restrict__ tick, unsigned long long* __restrict__ state,
    const unsigned* __restrict__ AdjU,
    const float* __restrict__ g1w, const float* __restrict__ g1b,
    const float* __restrict__ g2w, const float* __restrict__ g2b,
    const float* __restrict__ aw1, const float* __restrict__ ab1,
    const float* __restrict__ aw2, const float* __restrict__ ab2,
    float* __restrict__ z2g) {
  __shared__ float SHF[8832];  // 35328 B union
  const int tid = threadIdx.x;
  const int bid = blockIdx.x;

  if (bid >= nb && bid < nb + nscan) {
    // ======== decoupled-lookback exclusive scan, 1024 elems/tile ========
    unsigned* sh = (unsigned*)SHF;  // [0]=tile [1]=total [2]=base [4..7]=warpsum
    const int l = tid & 63, w = tid >> 6;
    if (tid == 0) sh[0] = atomicAdd(tick, 1u);
    __syncthreads();
    const unsigned tile = sh[0];
    const int i0 = (int)tile * 1024 + tid * 4;
    unsigned v0 = 0, v1 = 0, v2 = 0, v3 = 0;
    if (i0 + 4 <= n) {
      uint4 u4 = *(const uint4*)(cnt + i0);
      v0 = u4.x; v1 = u4.y; v2 = u4.z; v3 = u4.w;
    } else if (i0 < n) {
      v0 = cnt[i0];
      if (i0 + 1 < n) v1 = cnt[i0 + 1];
      if (i0 + 2 < n) v2 = cnt[i0 + 2];
      if (i0 + 3 < n) v3 = cnt[i0 + 3];
    }
    unsigned tsum = v0 + v1 + v2 + v3;
    unsigned inc = tsum;
#pragma unroll
    for (int o = 1; o < 64; o <<= 1) {
      unsigned u = __shfl_up(inc, o);
      if (l >= o) inc += u;
    }
    if (l == 63) sh[4 + w] = inc;
    __syncthreads();
    if (tid == 0) {
      unsigned a = 0;
      for (int i = 0; i < 4; ++i) {
        unsigned c = sh[4 + i];
        sh[4 + i] = a;
        a += c;
      }
      sh[1] = a;
    }
    __syncthreads();
    const unsigned texc = sh[4 + w] + inc - tsum;
    if (tid == 0) {
      const unsigned total = sh[1];
      unsigned run = 0;
      if (tile == 0) {
        __hip_atomic_store(&state[0], (2ULL << 32) | (unsigned long long)total,
                           __ATOMIC_RELEASE, __HIP_MEMORY_SCOPE_AGENT);
      } else {
        __hip_atomic_store(&state[tile], (1ULL << 32) | (unsigned long long)total,
                           __ATOMIC_RELEASE, __HIP_MEMORY_SCOPE_AGENT);
        int t2 = (int)tile - 1;
        while (t2 >= 0) {
          unsigned long long sv;
          do {
            sv = __hip_atomic_load(&state[t2], __ATOMIC_ACQUIRE, __HIP_MEMORY_SCOPE_AGENT);
          } while ((sv >> 32) == 0ULL);
          run += (unsigned)sv;
          if ((sv >> 32) == 2ULL) break;
          --t2;
        }
        __hip_atomic_store(&state[tile], (2ULL << 32) | (unsigned long long)(run + total),
                           __ATOMIC_RELEASE, __HIP_MEMORY_SCOPE_AGENT);
      }
      sh[2] = run;
      if (tile == (unsigned)(nscan - 1)) off[n] = run + total;
    }
    __syncthreads();
    unsigned run2 = sh[2] + texc;
    if (i0 < n) {
      off[i0] = run2;
      run2 += v0;
      if (i0 + 1 < n) {
        off[i0 + 1] = run2;
        run2 += v1;
        if (i0 + 2 < n) {
          off[i0 + 2] = run2;
          run2 += v2;
          if (i0 + 3 < n) off[i0 + 3] = run2;
        }
      }
    }
    return;
  }
  if (bid == nb + nscan) {
    // ======== GCN x2 + pool + MLP -> z2 (256 threads, parallel reductions) ========
    float* L0 = SHF;
    float* L1 = SHF + 4160;
    float* sdv = SHF + 8320;
    float* sts = sdv + 64;
    float* sgp = sts + 64;
    float* sz1 = sgp + 64;
    float* part = sz1 + 64;
    const int kk6 = tid & 63, mq = tid >> 6;
    for (int idx = tid; idx < 4096; idx += 256) {
      int r = idx >> 6, c = idx & 63;
      L0[r * 65 + c] = (float)AdjU[idx];
    }
    __syncthreads();
    {
      float p = 0.f;
      for (int c = mq * 16; c < mq * 16 + 16; ++c) p += L0[kk6 * 65 + c];
      part[mq * 64 + kk6] = p;
    }
    __syncthreads();
    if (tid < 64)
      sdv[tid] = rsqrtf(1.f + part[tid] + part[64 + tid] + part[128 + tid] + part[192 + tid]);
    __syncthreads();
    {
      float p = 0.f;
      for (int c = mq * 16; c < mq * 16 + 16; ++c) p += L0[kk6 * 65 + c] * sdv[c];
      part[mq * 64 + kk6] = p;
    }
    __syncthreads();
    if (tid < 64) sts[tid] = part[tid] + part[64 + tid] + part[128 + tid] + part[192 + tid];
    __syncthreads();
    for (int idx = tid; idx < 4096; idx += 256) {
      int d = idx >> 6, c = idx & 63;
      L1[d * 65 + c] = fmaxf(fmaf(g1w[c], fmaf(sts[d], sdv[d], sdv[d] * sdv[d]), g1b[c]), 0.f);
    }
    __syncthreads();
    const int i2 = tid >> 2, j0 = (tid & 3) << 4;
    float xw[16];
#pragma unroll
    for (int q = 0; q < 16; ++q) xw[q] = 0.f;
    for (int m = 0; m < 64; ++m) {
      float hm = L1[i2 * 65 + m];
      const float* wp = g2w + m * 64 + j0;
#pragma unroll
      for (int q = 0; q < 16; ++q) xw[q] = fmaf(hm, wp[q], xw[q]);
    }
    __syncthreads();
#pragma unroll
    for (int q = 0; q < 16; ++q) L1[i2 * 65 + j0 + q] = xw[q];
    __syncthreads();
    float a[16];
#pragma unroll
    for (int q = 0; q < 16; ++q) a[q] = 0.f;
    for (int s2 = 0; s2 < 64; ++s2) {
      float wv = L0[i2 * 65 + s2] * sdv[s2];
#pragma unroll
      for (int q = 0; q < 16; ++q) a[q] = fmaf(wv, L1[s2 * 65 + j0 + q], a[q]);
    }
    float di = sdv[i2], sc = di * di;
    float h2v[16];
#pragma unroll
    for (int q = 0; q < 16; ++q)
      h2v[q] = fmaf(a[q], di, fmaf(sc, L1[i2 * 65 + j0 + q], g2b[j0 + q]));
    __syncthreads();
#pragma unroll
    for (int q = 0; q < 16; ++q) L1[i2 * 65 + j0 + q] = h2v[q];
    __syncthreads();
    {
      float p = 0.f;
      for (int r = mq * 16; r < mq * 16 + 16; ++r) p += L1[r * 65 + kk6];
      part[mq * 64 + kk6] = p;
    }
    __syncthreads();
    if (tid < 64)
      sgp[tid] = (part[tid] + part[64 + tid] + part[128 + tid] + part[192 + tid]) * 0.015625f;
    __syncthreads();
    {
      float p = 0.f;
      for (int m = mq * 16; m < mq * 16 + 16; ++m) p = fmaf(sgp[m], aw1[m * 64 + kk6], p);
      part[mq * 64 + kk6] = p;
    }
    __syncthreads();
    if (tid < 64)
      sz1[tid] = fmaxf(ab1[tid] + part[tid] + part[64 + tid] + part[128 + tid] + part[192 + tid], 0.f);
    __syncthreads();
    {
      float p = 0.f;
      for (int m = mq * 16; m < mq * 16 + 16; ++m) p = fmaf(sz1[m], aw2[m * 64 + kk6], p);
      part[mq * 64 + kk6] = p;
    }
    __syncthreads();
    if (tid < 64)
      z2g[tid] = fmaxf(ab2[tid] + part[tid] + part[64 + tid] + part[128 + tid] + part[192 + tid], 0.f);
    return;
  }

  // ======== node MFMA path ========
  _Float16* bWr = (_Float16*)SHF;
  _Float16* bAd = (_Float16*)(SHF + 2048);
  _Float16* bAs = (_Float16*)(SHF + 3072);
  _Float16* cmT = (_Float16*)(SHF + 4096);
  const int lane = tid & 63;
  const int wave = tid >> 6;
  for (int slot = tid; slot < 512; slot += 256) {
    int g = slot >> 7;
    int c = (slot >> 6) & 1;
    int l = slot & 63;
    int col = g * 16 + (l & 15);
    int kb0 = c * 32 + ((l >> 4) << 3);
#pragma unroll
    for (int j = 0; j < 8; ++j) bWr[slot * 8 + j] = (_Float16)Wr[(kb0 + j) * 64 + col];
  }
  {
    int slot = tid;
    int g2 = slot >> 7;
    int c = (slot >> 6) & 1;
    int l = slot & 63;
    int col = g2 * 16 + (l & 15);
    int kb0 = c * 32 + ((l >> 4) << 3);
#pragma unroll
    for (int j = 0; j < 8; ++j) {
      bAd[slot * 8 + j] = (_Float16)Wg1[(kb0 + j) * 32 + col];
      bAs[slot * 8 + j] = (_Float16)Wg1[(64 + kb0 + j) * 32 + col];
    }
  }
  __syncthreads();
  const int tile = bid * 4 + wave;
  if (tile >= ntiles) return;
  const int base = tile << 4;
  const int row = lane & 15;
  const int kb = (lane >> 4) << 3;
  const int nodeA = min(base + row, n - 1);
  const float* xp = x + (size_t)nodeA * 64;
  float xv[8], xh[8];
  *(float4*)&xv[0] = *(const float4*)(xp + kb);
  *(float4*)&xv[4] = *(const float4*)(xp + kb + 4);
  *(float4*)&xh[0] = *(const float4*)(xp + 32 + kb);
  *(float4*)&xh[4] = *(const float4*)(xp + 32 + kb + 4);
  float s1 = 0.f, s2 = 0.f;
#pragma unroll
  for (int j = 0; j < 8; ++j) {
    s1 += xv[j] + xh[j];
    s2 += xv[j] * xv[j] + xh[j] * xh[j];
  }
  s1 += __shfl_xor(s1, 16);
  s1 += __shfl_xor(s1, 32);
  s2 += __shfl_xor(s2, 16);
  s2 += __shfl_xor(s2, 32);
  float mean = s1 * 0.015625f;
  float var = fmaf(-mean, mean, s2 * 0.015625f);
  float rstd = rsqrtf(var + 1e-5f);
  half8 aLo, aHi;
#pragma unroll
  for (int j = 0; j < 8; ++j) {
    aLo[j] = (_Float16)((xv[j] - mean) * rstd);
    aHi[j] = (_Float16)((xh[j] - mean) * rstd);
  }
  f32x4 accH[4];
#pragma unroll
  for (int g = 0; g < 4; ++g) {
    f32x4 z4 = {0.f, 0.f, 0.f, 0.f};
    z4 = __builtin_amdgcn_mfma_f32_16x16x32_f16(aLo, *(const half8*)&bWr[(g * 128 + lane) * 8], z4, 0, 0, 0);
    z4 = __builtin_amdgcn_mfma_f32_16x16x32_f16(aHi, *(const half8*)&bWr[(g * 128 + 64 + lane) * 8], z4, 0, 0, 0);
    accH[g] = z4;
  }
  float cm[4][4];
  float p1[4] = {0.f, 0.f, 0.f, 0.f}, p2[4] = {0.f, 0.f, 0.f, 0.f};
#pragma unroll
  for (int g = 0; g < 4; ++g)
#pragma unroll
    for (int r = 0; r < 4; ++r) {
      float hv = accH[g][r];
      float m = fminf(sqrtf(fmaf(hv, hv, 1e-8f)), 10.f);
      cm[g][r] = m;
      p1[r] += m;
      p2[r] += m * m;
    }
#pragma unroll
  for (int o = 1; o <= 8; o <<= 1)
#pragma unroll
    for (int r = 0; r < 4; ++r) {
      p1[r] += __shfl_xor(p1[r], o);
      p2[r] += __shfl_xor(p2[r], o);
    }
  const int rgrp = (lane >> 4) << 2;
#pragma unroll
  for (int g = 0; g < 4; ++g)
#pragma unroll
    for (int r = 0; r < 4; ++r)
      cmT[((wave * 16) + rgrp + r) * 72 + g * 16 + (lane & 15)] = (_Float16)cm[g][r];
  half8 cLo = *(const half8*)&cmT[((wave * 16) + row) * 72 + kb];
  half8 cHi = *(const half8*)&cmT[((wave * 16) + row) * 72 + 32 + kb];
  f32x4 accAd[2], accAs[2];
#pragma unroll
  for (int g2 = 0; g2 < 2; ++g2) {
    f32x4 z4 = {0.f, 0.f, 0.f, 0.f};
    z4 = __builtin_amdgcn_mfma_f32_16x16x32_f16(cLo, *(const half8*)&bAd[(g2 * 128 + lane) * 8], z4, 0, 0, 0);
    z4 = __builtin_amdgcn_mfma_f32_16x16x32_f16(cHi, *(const half8*)&bAd[(g2 * 128 + 64 + lane) * 8], z4, 0, 0, 0);
    accAd[g2] = z4;
    f32x4 w4 = {0.f, 0.f, 0.f, 0.f};
    w4 = __builtin_amdgcn_mfma_f32_16x16x32_f16(cLo, *(const half8*)&bAs[(g2 * 128 + lane) * 8], w4, 0, 0, 0);
    w4 = __builtin_amdgcn_mfma_f32_16x16x32_f16(cHi, *(const half8*)&bAs[(g2 * 128 + 64 + lane) * 8], w4, 0, 0, 0);
    accAs[g2] = w4;
  }
  const float b2r = b2[0];
  float c0v[2], g1v[2], w2v[2];
#pragma unroll
  for (int g2 = 0; g2 < 2; ++g2) {
    int k = g2 * 16 + (lane & 15);
    c0v[g2] = C0G1[k];
    g1v[g2] = C0G1[32 + k];
    w2v[g2] = w2[k];
  }
  float zp[4];
#pragma unroll
  for (int r = 0; r < 4; ++r) {
    float meanE = p1[r] * 0.015625f;
    float varE = fmaf(-meanE, meanE, p2[r] * 0.015625f);
    float rstdE = rsqrtf(varE + 1e-5f);
    float zz = 0.f;
#pragma unroll
    for (int g2 = 0; g2 < 2; ++g2) {
      float pre = fmaf(rstdE, fmaf(-meanE, g1v[g2], accAd[g2][r] + accAs[g2][r]), c0v[g2]);
      zz = fmaf(fmaxf(pre, 0.f), w2v[g2], zz);
    }
    zp[r] = zz;
  }
#pragma unroll
  for (int o = 1; o <= 8; o <<= 1)
#pragma unroll
    for (int r = 0; r < 4; ++r) zp[r] += __shfl_xor(zp[r], o);
  float csv[4], snv[4];
#pragma unroll
  for (int r = 0; r < 4; ++r) {
    float coup = 1.f / (1.f + expf(-(zp[r] + b2r)));
    float ph = fminf(0.3f * coup, MAXPH);
    sincosf(ph, &snv[r], &csv[r]);
  }
  const int colb = lane & 15;
#pragma unroll
  for (int r = 0; r < 4; ++r) {
    int node = base + rgrp + r;
    if (node >= n) break;
#pragma unroll
    for (int g = 0; g < 4; ++g) {
      int col = g * 16 + colb;
      float hv = accH[g][r];
      __hip_bfloat16 hb = __float2bfloat16(hv);
      R[(size_t)node * 128 + col] = *(ushort_t*)&hb;
      Crh[(size_t)node * 64 + col] = __float2half(hv * csv[r]);
      Srh[(size_t)node * 64 + col] = __float2half(hv * snv[r]);
    }
    ushort_t* ap = (ushort_t*)(AdP + (size_t)node * 64);
#pragma unroll
    for (int g2 = 0; g2 < 2; ++g2) {
      int col = g2 * 16 + colb;
      __hip_bfloat16 ab = __float2bfloat16(accAd[g2][r]);
      ap[col] = *(ushort_t*)&ab;
      __hip_bfloat16 sb2 = __float2bfloat16(accAs[g2][r]);
      R[(size_t)node * 128 + 64 + col] = *(ushort_t*)&sb2;
    }
    if (colb == 0) {
      float* sp = (float*)(R + (size_t)node * 128 + 96);
      sp[0] = p1[r];
      sp[1] = p2[r];
      float* dp = AdP + (size_t)node * 64;
      dp[16] = p1[r];
      dp[17] = p2[r];
    }
  }
}

// ---- kPhaseTanh: blocks [0,1024) = lane-per-edge phase -> recs; [1024,1040) = tanh
__global__ __launch_bounds__(256) void kPhaseTanh(
    const int* __restrict__ ei, const float* __restrict__ ew, int ne,
    const ushort_t* __restrict__ R, const float* __restrict__ AdP,
    const float* __restrict__ C0G1, const float* __restrict__ w2,
    const float* __restrict__ b2,
    const unsigned* __restrict__ off, unsigned* __restrict__ cur,
    int2* __restrict__ recSC,
    const float* __restrict__ z2g, const float* __restrict__ aw3,
    const float* __restrict__ ab3, float* __restrict__ pG) {
  if (blockIdx.x >= 1024) {
    int rc = (blockIdx.x - 1024) * 256 + threadIdx.x;
    float a = ab3[rc];
    for (int m = 0; m < 64; ++m) a = fmaf(z2g[m], aw3[m * 4096 + rc], a);
    pG[rc] = tanhf(a);
    return;
  }
  const float b2r = b2[0];
  int t = blockIdx.x * 256 + threadIdx.x;
  int st = 1024 * 256;
  for (int e = t; e < ne; e += st) {
    int s = ei[e];
    int d = ei[ne + e];
    const ushort_t* rs = R + (size_t)s * 128;
    const float* bp = AdP + (size_t)d * 64;
    float2 ps = *(const float2*)(rs + 96);
    float2 pd = *(const float2*)(bp + 16);
    float meanE = (ps.x + pd.x) * 0.0078125f;
    float varE = fmaf(-meanE, meanE, (ps.y + pd.y) * 0.0078125f);
    float rstdE = rsqrtf(varE + 1e-5f);
    const uint4* asq = (const uint4*)(rs + 64);
    const uint4* adq = (const uint4*)bp;
    float z = b2r;
#pragma unroll
    for (int q = 0; q < 4; ++q) {
      uint4 ua = adq[q];
      uint4 ub = asq[q];
      unsigned av[4] = {ua.x, ua.y, ua.z, ua.w};
      unsigned bv[4] = {ub.x, ub.y, ub.z, ub.w};
#pragma unroll
      for (int p = 0; p < 4; ++p) {
        int k0 = q * 8 + p * 2;
        float a0 = __uint_as_float(av[p] << 16);
        float a1 = __uint_as_float(av[p] & 0xFFFF0000u);
        float b0 = __uint_as_float(bv[p] << 16);
        float b1 = __uint_as_float(bv[p] & 0xFFFF0000u);
        float pre0 = fmaf(rstdE, fmaf(-meanE, C0G1[32 + k0], a0 + b0), C0G1[k0]);
        float pre1 = fmaf(rstdE, fmaf(-meanE, C0G1[32 + k0 + 1], a1 + b1), C0G1[k0 + 1]);
        z = fmaf(fmaxf(pre0, 0.f), w2[k0], z);
        z = fmaf(fmaxf(pre1, 0.f), w2[k0 + 1], z);
      }
    }
    float coup = 1.f / (1.f + expf(-z));
    float cw = fminf(fmaxf(ew[e], 0.1f), 2.f);
    float ph = fminf(0.3f * coup * cw, MAXPH);
    float sn, cs;
    sincosf(ph, &sn, &cs);
    unsigned p = atomicAdd(&cur[d], 1u);
    unsigned pos = off[d] + p;
    __half2 h2 = __floats2half2_rn(cs, sn);
    int2 rec;
    rec.x = s;
    rec.y = *(int*)&h2;
    recSC[pos] = rec;
  }
}

// ---- kScatterExpm: blocks [0,G-1) = wave-per-node gather; block G-1 = expm
__global__ __launch_bounds__(1024) void kScatterExpm(
    const unsigned* __restrict__ off, const int2* __restrict__ recSC,
    const ushort_t* __restrict__ R,
    __half* __restrict__ Crh, __half* __restrict__ Srh, int n,
    const float* __restrict__ pG, float* __restrict__ UrT, float* __restrict__ UiT) {
  __shared__ float Br[64 * 65], Bi[64 * 65];
  __shared__ float Xr[64 * 68], Xi[64 * 68];
  __shared__ float rowsum[64];
  __shared__ int sSh;
  const int tid = threadIdx.x;
  if (blockIdx.x == gridDim.x - 1) {
    const float SC0 = 0.05f;  // 0.1 * 0.5
    for (int idx = tid; idx < 4096; idx += 1024) {
      int r = idx >> 6, c = idx & 63;
      float pr = pG[r * 64 + c], pt = pG[c * 64 + r];
      Br[r * 65 + c] = (pr - pt) * SC0;
      Bi[r * 65 + c] = (pr + pt) * SC0;
    }
    __syncthreads();
    if (tid < 64) {
      float a = 0.f;
      for (int c = 0; c < 64; ++c) a += fabsf(Br[tid * 65 + c]) + fabsf(Bi[tid * 65 + c]);
      rowsum[tid] = a;
    }
    __syncthreads();
    if (tid == 0) {
      float m = 0.f;
      for (int i2 = 0; i2 < 64; ++i2) m = fmaxf(m, rowsum[i2]);
      int s = 0;
      while (m > 0.25f && s < 16) {
        m *= 0.5f;
        ++s;
      }
      sSh = s;
    }
    __syncthreads();
    const int sVal = sSh;
    const float scale = ldexpf(1.f, -sVal);
    for (int idx = tid; idx < 4096; idx += 1024) {
      int r = idx >> 6, c = idx & 63;
      float br = Br[r * 65 + c] * scale;
      float bi = Bi[r * 65 + c] * scale;
      Br[r * 65 + c] = br;
      Bi[r * 65 + c] = bi;
      Xr[r * 68 + c] = (r == c ? 1.f : 0.f) + br * (1.f / 6.f);
      Xi[r * 68 + c] = bi * (1.f / 6.f);
    }
    __syncthreads();
    const int i = tid >> 4, j0 = (tid & 15) << 2;
    for (int kk = 5; kk >= 1; --kk) {
      float ar[4] = {0, 0, 0, 0}, ai[4] = {0, 0, 0, 0};
      for (int m = 0; m < 64; ++m) {
        float br = Br[i * 65 + m], bi = Bi[i * 65 + m];
        float4 xr4 = *(const float4*)&Xr[m * 68 + j0];
        float4 xi4 = *(const float4*)&Xi[m * 68 + j0];
        float xr[4] = {xr4.x, xr4.y, xr4.z, xr4.w};
        float xi[4] = {xi4.x, xi4.y, xi4.z, xi4.w};
#pragma unroll
        for (int q = 0; q < 4; ++q) {
          ar[q] = fmaf(br, xr[q], fmaf(-bi, xi[q], ar[q]));
          ai[q] = fmaf(br, xi[q], fmaf(bi, xr[q], ai[q]));
        }
      }
      __syncthreads();
      float inv = 1.f / (float)kk;
#pragma unroll
      for (int q = 0; q < 4; ++q) {
        int c = j0 + q;
        Xr[i * 68 + c] = (i == c ? 1.f : 0.f) + ar[q] * inv;
        Xi[i * 68 + c] = ai[q] * inv;
      }
      __syncthreads();
    }
    for (int sq = 0; sq < sVal; ++sq) {
      float ar[4] = {0, 0, 0, 0}, ai[4] = {0, 0, 0, 0};
      for (int m = 0; m < 64; ++m) {
        float br = Xr[i * 68 + m], bi = Xi[i * 68 + m];
        float4 xr4 = *(const float4*)&Xr[m * 68 + j0];
        float4 xi4 = *(const float4*)&Xi[m * 68 + j0];
        float xr[4] = {xr4.x, xr4.y, xr4.z, xr4.w};
        float xi[4] = {xi4.x, xi4.y, xi4.z, xi4.w};
#pragma unroll
        for (int q = 0; q < 4; ++q) {
          ar[q] = fmaf(br, xr[q], fmaf(-bi, xi[q], ar[q]));
          ai[q] = fmaf(br, xi[q], fmaf(bi, xr[q], ai[q]));
        }
      }
      __syncthreads();
#pragma unroll
      for (int q = 0; q < 4; ++q) {
        Xr[i * 68 + j0 + q] = ar[q];
        Xi[i * 68 + j0 + q] = ai[q];
      }
      __syncthreads();
    }
    for (int idx = tid; idx < 4096; idx += 1024) {
      int a2 = idx >> 6, b2i = idx & 63;
      UrT[idx] = Xr[b2i * 68 + a2];
      UiT[idx] = Xi[b2i * 68 + a2];
    }
    return;
  }
  const int lane = tid & 63;
  const int wid = (blockIdx.x * 1024 + tid) >> 6;
  const int nw = ((gridDim.x - 1) * 1024) >> 6;
  for (int d = wid; d < n; d += nw) {
    unsigned u0 = off[d], u1 = off[d + 1];
    float accR = 0.f, accI = 0.f;
    unsigned j = u0;
    for (; j + 8 <= u1; j += 8) {
      int s8[8];
      float2 c8[8];
#pragma unroll
      for (int k = 0; k < 8; ++k) {
        int2 rec = recSC[j + k];
        s8[k] = rec.x;
        __half2 h2 = *(__half2*)&rec.y;
        c8[k] = __half22float2(h2);
      }
#pragma unroll
      for (int k = 0; k < 8; ++k) {
        float hv = bf2f(R[(size_t)s8[k] * 128 + lane]);
        accR = fmaf(hv, c8[k].x, accR);
        accI = fmaf(hv, c8[k].y, accI);
      }
    }
    for (; j < u1; ++j) {
      int2 rec = recSC[j];
      __half2 h2 = *(__half2*)&rec.y;
      float2 c = __half22float2(h2);
      float hv = bf2f(R[(size_t)rec.x * 128 + lane]);
      accR = fmaf(hv, c.x, accR);
      accI = fmaf(hv, c.y, accI);
    }
    size_t idx = (size_t)d * 64 + lane;
    Crh[idx] = __float2half(__half2float(Crh[idx]) + accR);
    Srh[idx] = __float2half(__half2float(Srh[idx]) + accI);
  }
}

// ---- kFinalM: MFMA GEMM — OutR=[Cr|Sr]@[UrT;-UiT], OutI=[Cr|Sr]@[UiT;UrT]; +0.5*LN(x)
__global__ __launch_bounds__(256) void kFinalM(
    const float* __restrict__ x, const __half* __restrict__ Crh,
    const __half* __restrict__ Srh, const float* __restrict__ UrT,
    const float* __restrict__ UiT, float* __restrict__ out, int n, int ntiles) {
  __shared__ _Float16 bR[1024][8];
  __shared__ _Float16 bI[1024][8];
  __shared__ float xrT[4][16][65];
  const int tid = threadIdx.x;
  const int lane = tid & 63;
  const int wave = tid >> 6;
  for (int slot = tid; slot < 1024; slot += 256) {
    int g = slot >> 8;
    int c = (slot >> 6) & 3;
    int l = slot & 63;
    int col = g * 16 + (l & 15);
    int kb = c * 32 + ((l >> 4) << 3);
#pragma unroll
    for (int j = 0; j < 8; ++j) {
      int k = kb + j;
      float vr, vi;
      if (k < 64) {
        vr = UrT[k * 64 + col];
        vi = UiT[k * 64 + col];
      } else {
        vr = -UiT[(k - 64) * 64 + col];
        vi = UrT[(k - 64) * 64 + col];
      }
      bR[slot][j] = (_Float16)vr;
      bI[slot][j] = (_Float16)vi;
    }
  }
  __syncthreads();
  const int tile = blockIdx.x * 4 + wave;
  if (tile >= ntiles) return;
  const int base = tile << 4;
  for (int nn = 0; nn < 16; ++nn) {
    int node = min(base + nn, n - 1);
    float xv = x[(size_t)node * 64 + lane];
    float s1 = wsum64(xv);
    float s2 = wsum64(xv * xv);
    float mean = s1 * 0.015625f;
    float var = fmaf(-mean, mean, s2 * 0.015625f);
    xrT[wave][nn][lane] = (xv - mean) * rsqrtf(var + 1e-5f);
  }
  const int row = lane & 15;
  const int node = min(base + row, n - 1);
  const int kb = (lane >> 4) << 3;
  const _Float16* crp = (const _Float16*)(Crh + (size_t)node * 64);
  const _Float16* srp = (const _Float16*)(Srh + (size_t)node * 64);
  half8 a0 = *(const half8*)(crp + kb);
  half8 a1 = *(const half8*)(crp + 32 + kb);
  half8 a2 = *(const half8*)(srp + kb);
  half8 a3 = *(const half8*)(srp + 32 + kb);
  const size_t imag_off = (size_t)n * 64;
  const int rgrp = (lane >> 4) << 2;
#pragma unroll
  for (int g = 0; g < 4; ++g) {
    f32x4 accR = {0.f, 0.f, 0.f, 0.f};
    f32x4 accI = {0.f, 0.f, 0.f, 0.f};
    const int sb = g * 256 + lane;
    accR = __builtin_amdgcn_mfma_f32_16x16x32_f16(a0, *(const half8*)&bR[sb][0], accR, 0, 0, 0);
    accR = __builtin_amdgcn_mfma_f32_16x16x32_f16(a1, *(const half8*)&bR[sb + 64][0], accR, 0, 0, 0);
    accR = __builtin_amdgcn_mfma_f32_16x16x32_f16(a2, *(const half8*)&bR[sb + 128][0], accR, 0, 0, 0);
    accR = __builtin_amdgcn_mfma_f32_16x16x32_f16(a3, *(const half8*)&bR[sb + 192][0], accR, 0, 0, 0);
    accI = __builtin_amdgcn_mfma_f32_16x16x32_f16(a0, *(const half8*)&bI[sb][0], accI, 0, 0, 0);
    accI = __builtin_amdgcn_mfma_f32_16x16x32_f16(a1, *(const half8*)&bI[sb + 64][0], accI, 0, 0, 0);
    accI = __builtin_amdgcn_mfma_f32_16x16x32_f16(a2, *(const half8*)&bI[sb + 128][0], accI, 0, 0, 0);
    accI = __builtin_amdgcn_mfma_f32_16x16x32_f16(a3, *(const half8*)&bI[sb + 192][0], accI, 0, 0, 0);
    const int col = g * 16 + (lane & 15);
#pragma unroll
    for (int reg = 0; reg < 4; ++reg) {
      int r = base + rgrp + reg;
      if (r < n) {
        out[(size_t)r * 64 + col] = 0.5f * (accR[reg] + xrT[wave][rgrp + reg][col]);
        out[imag_off + (size_t)r * 64 + col] = 0.5f * accI[reg];
      }
    }
  }
}

extern "C" void kernel_launch(void* const* d_in, const int* in_sizes, int n_in,
                              void* d_out, int out_size, void* d_ws, size_t ws_size,
                              hipStream_t stream) {
  const float* x    = (const float*)d_in[0];
  const int*   ei   = (const int*)d_in[1];
  const float* ew   = (const float*)d_in[2];
  const float* Wr   = (const float*)d_in[3];
  const float* ln_g = (const float*)d_in[5];
  const float* ln_b = (const float*)d_in[6];
  const float* w1   = (const float*)d_in[7];
  const float* b1   = (const float*)d_in[8];
  const float* w2   = (const float*)d_in[9];
  const float* b2   = (const float*)d_in[10];
  const float* g1w  = (const float*)d_in[11];
  const float* g1b  = (const float*)d_in[12];
  const float* g2w  = (const float*)d_in[13];
  const float* g2b  = (const float*)d_in[14];
  const float* aw1  = (const float*)d_in[15];
  const float* ab1  = (const float*)d_in[16];
  const float* aw2  = (const float*)d_in[17];
  const float* ab2  = (const float*)d_in[18];
  const float* aw3  = (const float*)d_in[19];
  const float* ab3  = (const float*)d_in[20];
  const int n = in_sizes[0] / 64;
  const int e = in_sizes[1] / 2;
  float* out = (float*)d_out;

  const int nscan = (n + 1023) >> 10;

  float* ws = (float*)d_ws;
  float* Wg1  = ws;                           // 4096
  float* C0G1 = ws + 4096;                    // 64
  float* UrT  = ws + 4160;                    // 4096
  float* UiT  = ws + 8256;                    // 4096
  float* z2g  = ws + 12352;                   // 64
  float* pG   = ws + 12416;                   // 4096
  unsigned* AdjU = (unsigned*)(ws + 20544);   // 4096 u32 — zero region start
  unsigned* cnt = AdjU + 4096;                // n
  unsigned* cur = cnt + n;                    // n
  unsigned long long* state = (unsigned long long*)(cur + n);  // nscan u64 (8B-aligned)
  unsigned* tick = (unsigned*)(state + nscan);                 // 2 u32 (tick + pad)
  unsigned* off = tick + 2;                   // n+1 (fully written by scan)
  size_t zeroEndF = 20544 + 4096 + 2 * (size_t)n + 2 * (size_t)nscan + 2;
  size_t p0 = (zeroEndF + (size_t)n + 1 + 63) & ~(size_t)63;
  int2* recSC = (int2*)(ws + p0);             // e int2
  size_t p2 = (p0 + 2 * (size_t)e + 63) & ~(size_t)63;
  ushort_t* R = (ushort_t*)(ws + p2);         // 64n f32-units
  size_t p3 = (p2 + 64 * (size_t)n + 63) & ~(size_t)63;
  float* AdP = ws + p3;                       // 64n f32-units
  size_t p4 = (p3 + 64 * (size_t)n + 63) & ~(size_t)63;
  __half* Crh = (__half*)(ws + p4);           // 32n
  size_t p5 = (p4 + 32 * (size_t)n + 63) & ~(size_t)63;
  __half* Srh = (__half*)(ws + p5);           // 32n

  const int ntiles = (n + 15) >> 4;
  const int nb = (ntiles + 3) >> 2;

  hipMemsetAsync(AdjU, 0, (4096 + 2 * (size_t)n + 2 * (size_t)nscan + 2) * 4, stream);
  kCountPrep<<<1025, 256, 0, stream>>>(ei, e, cnt, AdjU, ln_g, ln_b, w1, b1, Wg1, C0G1);
  kNodeMSG3<<<nb + nscan + 1, 256, 0, stream>>>(
      x, Wr, Wg1, C0G1, w2, b2, R, AdP, Crh, Srh, n, ntiles, nb, nscan, cnt, off,
      tick, state, AdjU, g1w, g1b, g2w, g2b, aw1, ab1, aw2, ab2, z2g);
  kPhaseTanh<<<1040, 256, 0, stream>>>(ei, ew, e, R, AdP, C0G1, w2, b2, off, cur, recSC,
                                       z2g, aw3, ab3, pG);
  kScatterExpm<<<513, 1024, 0, stream>>>(off, recSC, R, Crh, Srh, n, pG, UrT, UiT);
  kFinalM<<<nb, 256, 0, stream>>>(x, Crh, Srh, UrT, UiT, out, n, ntiles);
}